// Round 1
// baseline (1919.128 us; speedup 1.0000x reference)
//
#include <hip/hip_runtime.h>
#include <hip/hip_bf16.h>
#include <math.h>

#define N_NODES 4096
#define C_DIM   384
#define B_DIM   8
#define K_NB    8
#define E_TOT   (N_NODES * K_NB)     // 32768
#define M_ROWS  (B_DIM * N_NODES)    // 32768

// ---------------- transpose + batch mean ----------------
// fea [B,C,N] -> X [B,N,C]; fm[n,c] = mean_b fea[b,c,n]
__global__ __launch_bounds__(256) void k_transpose_mean(
    const float* __restrict__ fea, float* __restrict__ X, float* __restrict__ fm) {
  __shared__ float t[32][33];
  __shared__ float acc[32][33];
  int n0 = blockIdx.x * 32, c0 = blockIdx.y * 32;
  int tx = threadIdx.x, ty = threadIdx.y;   // (32,8)
  for (int i = ty; i < 32; i += 8) acc[i][tx] = 0.0f;
  __syncthreads();
  for (int b = 0; b < B_DIM; b++) {
    for (int i = ty; i < 32; i += 8) {
      float v = fea[((size_t)b * C_DIM + (c0 + i)) * N_NODES + n0 + tx];
      t[i][tx] = v;
      acc[i][tx] += v;
    }
    __syncthreads();
    for (int i = ty; i < 32; i += 8)
      X[((size_t)b * N_NODES + (n0 + i)) * C_DIM + c0 + tx] = t[tx][i];
    __syncthreads();
  }
  for (int i = ty; i < 32; i += 8)
    fm[(size_t)(n0 + i) * C_DIM + c0 + tx] = acc[tx][i] * 0.125f;
}

// ---------------- squared norms ----------------
__global__ __launch_bounds__(64) void k_x2(const float* __restrict__ fm,
                                           float* __restrict__ x2) {
  int n = blockIdx.x;
  int lane = threadIdx.x;
  const float* r = fm + (size_t)n * C_DIM;
  float s = 0.0f;
  for (int c = lane; c < C_DIM; c += 64) s += r[c] * r[c];
  for (int d = 32; d > 0; d >>= 1) s += __shfl_down(s, d);
  if (lane == 0) x2[n] = s;
}

// ---------------- fused distance GEMM + partial top-8 ----------------
// blockIdx.x: i-tile (64 rows), blockIdx.y: j-chunk (1024 cols each, 4 chunks)
__global__ __launch_bounds__(256) void k_dist_topk(
    const float* __restrict__ fm, const float* __restrict__ x2,
    float* __restrict__ pv, int* __restrict__ pi) {
  __shared__ float As[16][65];
  __shared__ float Bs[16][65];
  __shared__ float Ds[64][65];
  __shared__ float topv[64][8];
  __shared__ int   topi[64][8];
  int i0 = blockIdx.x * 64;
  int jc = blockIdx.y;
  int jbeg = jc * 1024;
  int t = threadIdx.x;
  int tx = t & 15, ty = t >> 4;

  if (t < 64) {
    for (int q = 0; q < 8; q++) { topv[t][q] = 3.4e38f; topi[t][q] = -1; }
  }
  float x2i[4]; int iy[4], ix[4];
  for (int r = 0; r < 4; r++) {
    int i = i0 + ty * 4 + r;
    x2i[r] = x2[i];
    iy[r] = i >> 6; ix[r] = i & 63;
  }

  for (int j0 = jbeg; j0 < jbeg + 1024; j0 += 64) {
    float accv[4][4] = {};
    for (int cc = 0; cc < C_DIM; cc += 16) {
      __syncthreads();
      int kk = t & 15, ii = t >> 4;
      #pragma unroll
      for (int e = 0; e < 4; e++)
        As[kk][ii + e * 16] = fm[(size_t)(i0 + ii + e * 16) * C_DIM + cc + kk];
      #pragma unroll
      for (int e = 0; e < 4; e++)
        Bs[kk][ii + e * 16] = fm[(size_t)(j0 + ii + e * 16) * C_DIM + cc + kk];
      __syncthreads();
      #pragma unroll
      for (int kk2 = 0; kk2 < 16; kk2++) {
        float a[4], b[4];
        #pragma unroll
        for (int r = 0; r < 4; r++) a[r] = As[kk2][ty * 4 + r];
        #pragma unroll
        for (int s = 0; s < 4; s++) b[s] = Bs[kk2][tx * 4 + s];
        #pragma unroll
        for (int r = 0; r < 4; r++)
          #pragma unroll
          for (int s = 0; s < 4; s++) accv[r][s] += a[r] * b[s];
      }
    }
    __syncthreads();
    #pragma unroll
    for (int r = 0; r < 4; r++) {
      #pragma unroll
      for (int s = 0; s < 4; s++) {
        int j = j0 + tx * 4 + s;
        float d2 = x2i[r] + x2[j] - 2.0f * accv[r][s];
        float fd = sqrtf(fmaxf(d2, 0.0f));
        int jy = j >> 6, jx = j & 63;
        float dy = (float)(iy[r] - jy), dx = (float)(ix[r] - jx);
        float sd = sqrtf(dy * dy + dx * dx);
        Ds[ty * 4 + r][tx * 4 + s] = 0.7f * sd + 0.3f * fd;
      }
    }
    __syncthreads();
    if (t < 64) {
      for (int jj = 0; jj < 64; jj++) {
        float v = Ds[t][jj];
        if (v < topv[t][7]) {
          int p = 7;
          while (p > 0 && topv[t][p - 1] > v) {
            topv[t][p] = topv[t][p - 1]; topi[t][p] = topi[t][p - 1]; p--;
          }
          topv[t][p] = v; topi[t][p] = j0 + jj;
        }
      }
    }
    __syncthreads();
  }
  if (t < 64) {
    int i = i0 + t;
    for (int q = 0; q < 8; q++) {
      pv[((size_t)jc * N_NODES + i) * 8 + q] = topv[t][q];
      pi[((size_t)jc * N_NODES + i) * 8 + q] = topi[t][q];
    }
  }
}

// ---------------- merge 4 partial top-8 lists ----------------
__global__ __launch_bounds__(256) void k_topk_merge(
    const float* __restrict__ pv, const int* __restrict__ pi, int* __restrict__ tk) {
  int n = blockIdx.x * 256 + threadIdx.x;
  if (n >= N_NODES) return;
  int head[4] = {0, 0, 0, 0};
  for (int o = 0; o < 8; o++) {
    int bc = 0; float bv = 3.5e38f; int bi = 1 << 30;
    for (int c = 0; c < 4; c++) {
      if (head[c] < 8) {
        float cv = pv[((size_t)c * N_NODES + n) * 8 + head[c]];
        int   ci = pi[((size_t)c * N_NODES + n) * 8 + head[c]];
        if (cv < bv || (cv == bv && ci < bi)) { bv = cv; bi = ci; bc = c; }
      }
    }
    tk[n * 8 + o] = bi;
    head[bc]++;
  }
}

// ---------------- degree count ----------------
__global__ __launch_bounds__(256) void k_deg(const int* __restrict__ tk,
                                             int* __restrict__ deg) {
  int e = blockIdx.x * 256 + threadIdx.x;
  if (e < E_TOT) atomicAdd(&deg[tk[e]], 1);
}

// ---------------- exclusive scan (4096) + dinv ----------------
__global__ __launch_bounds__(256) void k_scan(const int* __restrict__ deg,
                                              int* __restrict__ offs,
                                              float* __restrict__ dinv) {
  __shared__ int ps[256];
  int t = threadIdx.x;
  int base = t * 16;
  int loc[16]; int s = 0;
  for (int i = 0; i < 16; i++) { int d = deg[base + i]; loc[i] = s; s += d; }
  ps[t] = s;
  __syncthreads();
  for (int d = 1; d < 256; d <<= 1) {
    int add = (t >= d) ? ps[t - d] : 0;
    __syncthreads();
    ps[t] += add;
    __syncthreads();
  }
  int cbase = (t == 0) ? 0 : ps[t - 1];
  for (int i = 0; i < 16; i++) offs[base + i] = cbase + loc[i];
  if (t == 255) offs[N_NODES] = ps[255];
  for (int i = 0; i < 16; i++)
    dinv[base + i] = 1.0f / sqrtf((float)deg[base + i]);
}

// ---------------- CSR fill ----------------
__global__ __launch_bounds__(256) void k_fill(const int* __restrict__ tk,
                                              const int* __restrict__ offs,
                                              int* __restrict__ cnt,
                                              int* __restrict__ insrc) {
  int e = blockIdx.x * 256 + threadIdx.x;
  if (e >= E_TOT) return;
  int i = e >> 3;
  int n = tk[e];
  int pos = offs[n] + atomicAdd(&cnt[n], 1);
  insrc[pos] = i;
}

// ---------------- per-node sort (determinism) ----------------
__global__ __launch_bounds__(256) void k_sort(const int* __restrict__ offs,
                                              int* __restrict__ insrc) {
  int n = blockIdx.x * 256 + threadIdx.x;
  if (n >= N_NODES) return;
  int beg = offs[n], end = offs[n + 1];
  for (int a = beg + 1; a < end; a++) {
    int v = insrc[a]; int p = a;
    while (p > beg && insrc[p - 1] > v) { insrc[p] = insrc[p - 1]; p--; }
    insrc[p] = v;
  }
}

// ---------------- generic fp32 GEMM C[M,N] = A[M,K] @ B[K,N], epilogue ----------------
__device__ __forceinline__ float gelu_f(float x) {
  const float k0 = 0.7978845608028654f;  // sqrt(2/pi)
  float x3 = x * x * x;
  return 0.5f * x * (1.0f + tanhf(k0 * (x + 0.044715f * x3)));
}

template <int EPI>  // 0 = none, 1 = bias+gelu
__global__ __launch_bounds__(256) void k_gemm(
    const float* __restrict__ A, const float* __restrict__ B,
    const float* __restrict__ bias, float* __restrict__ C,
    int M, int N, int K) {
  __shared__ float As[16][65];
  __shared__ float Bs[16][65];
  int m0 = blockIdx.x * 64, n0 = blockIdx.y * 64;
  int t = threadIdx.x, tx = t & 15, ty = t >> 4;
  float acc[4][4] = {};
  for (int cc = 0; cc < K; cc += 16) {
    __syncthreads();
    {
      int kk = t & 15, ii = t >> 4;
      #pragma unroll
      for (int e = 0; e < 4; e++)
        As[kk][ii + e * 16] = A[(size_t)(m0 + ii + e * 16) * K + cc + kk];
      int jj2 = t & 63, kr = t >> 6;
      #pragma unroll
      for (int e = 0; e < 4; e++) {
        int kk2 = kr * 4 + e;
        int col = n0 + jj2;
        Bs[kk2][jj2] = (col < N) ? B[(size_t)(cc + kk2) * N + col] : 0.0f;
      }
    }
    __syncthreads();
    #pragma unroll
    for (int kk = 0; kk < 16; kk++) {
      float a[4], b[4];
      #pragma unroll
      for (int r = 0; r < 4; r++) a[r] = As[kk][ty * 4 + r];
      #pragma unroll
      for (int s = 0; s < 4; s++) b[s] = Bs[kk][tx * 4 + s];
      #pragma unroll
      for (int r = 0; r < 4; r++)
        #pragma unroll
        for (int s = 0; s < 4; s++) acc[r][s] += a[r] * b[s];
    }
  }
  #pragma unroll
  for (int r = 0; r < 4; r++) {
    int m = m0 + ty * 4 + r;
    #pragma unroll
    for (int s = 0; s < 4; s++) {
      int n = n0 + tx * 4 + s;
      if (n < N) {
        float v = acc[r][s];
        if (EPI == 1) { v += bias[n]; v = gelu_f(v); }
        C[(size_t)m * N + n] = v;
      }
    }
  }
}

// ---------------- GCN aggregation: X += relu(dinv[n]*sum + bias) ----------------
__global__ __launch_bounds__(384) void k_gcn_agg(
    const float* __restrict__ xw, float* __restrict__ X,
    const float* __restrict__ bias, const float* __restrict__ dinv,
    const int* __restrict__ offs, const int* __restrict__ insrc) {
  int bn = blockIdx.x;          // b*4096 + n
  int b = bn >> 12, n = bn & 4095;
  int c = threadIdx.x;          // 384
  int beg = offs[n], end = offs[n + 1];
  const float* xwb = xw + (size_t)b * N_NODES * C_DIM;
  float s = 0.0f;
  for (int e = beg; e < end; e++) {
    int i = insrc[e];
    s += dinv[i] * xwb[(size_t)i * C_DIM + c];
  }
  float v = dinv[n] * s + bias[c];
  size_t o = (size_t)bn * C_DIM + c;
  X[o] += fmaxf(v, 0.0f);
}

// ---------------- final matvec (96 -> 1) + sigmoid ----------------
__global__ __launch_bounds__(256) void k_unc(
    const float* __restrict__ h2, const float* __restrict__ U3,
    const float* __restrict__ ub3, float* __restrict__ unc) {
  int r = blockIdx.x * 256 + threadIdx.x;
  if (r >= M_ROWS) return;
  const float* h = h2 + (size_t)r * 96;
  float s = 0.0f;
  #pragma unroll
  for (int c = 0; c < 96; c++) s += h[c] * U3[c];
  s += ub3[0];
  unc[r] = 1.0f / (1.0f + expf(-s));
}

// ---------------- out = fea * (1 + unc) ----------------
__global__ __launch_bounds__(256) void k_final(
    const float* __restrict__ fea, const float* __restrict__ unc,
    float* __restrict__ out) {
  size_t idx = (size_t)blockIdx.x * 256 + threadIdx.x;
  if (idx >= (size_t)B_DIM * C_DIM * N_NODES) return;
  int b = (int)(idx / ((size_t)C_DIM * N_NODES));
  int n = (int)(idx & (N_NODES - 1));
  out[idx] = fea[idx] * (1.0f + unc[(size_t)b * N_NODES + n]);
}

extern "C" void kernel_launch(void* const* d_in, const int* in_sizes, int n_in,
                              void* d_out, int out_size, void* d_ws, size_t ws_size,
                              hipStream_t stream) {
  const float* fea = (const float*)d_in[0];
  const float* W1  = (const float*)d_in[1];
  const float* b1  = (const float*)d_in[2];
  const float* W2  = (const float*)d_in[3];
  const float* b2  = (const float*)d_in[4];
  const float* W3  = (const float*)d_in[5];
  const float* b3  = (const float*)d_in[6];
  const float* U1  = (const float*)d_in[7];
  const float* ub1 = (const float*)d_in[8];
  const float* U2  = (const float*)d_in[9];
  const float* ub2 = (const float*)d_in[10];
  const float* U3  = (const float*)d_in[11];
  const float* ub3 = (const float*)d_in[12];
  float* out = (float*)d_out;

  char* ws = (char*)d_ws;
  const size_t SZ_X  = (size_t)M_ROWS * C_DIM * 4;        // 50331648
  float* X    = (float*)(ws);
  float* XW   = (float*)(ws + SZ_X);
  float* fm   = (float*)(ws + 2 * SZ_X);                  // N*C*4 = 6291456
  float* x2   = (float*)(ws + 2 * SZ_X + 6291456);        // 16384
  int*   tk   = (int*)  (ws + 2 * SZ_X + 6307840);        // 131072
  int*   deg  = (int*)  (ws + 2 * SZ_X + 6438912);        // 16384
  float* dinv = (float*)(ws + 2 * SZ_X + 6455296);        // 16384
  int*   offs = (int*)  (ws + 2 * SZ_X + 6471680);        // 16640
  int*   cnt  = (int*)  (ws + 2 * SZ_X + 6488320);        // 16384
  int*   insrc= (int*)  (ws + 2 * SZ_X + 6504704);        // 131072
  float* unc  = (float*)(ws + 2 * SZ_X + 6635776);        // 131072
  float* pv   = (float*)(ws + 2 * SZ_X + 6766848);        // 524288
  int*   pi   = (int*)  (ws + 2 * SZ_X + 7291136);        // 524288
  float* h1   = XW;                                       // [32768,192]
  float* h2   = (float*)(ws + SZ_X + (size_t)M_ROWS * 192 * 4); // [32768,96]

  // 1) transpose + mean
  k_transpose_mean<<<dim3(N_NODES / 32, C_DIM / 32), dim3(32, 8), 0, stream>>>(fea, X, fm);
  // 2) norms
  k_x2<<<N_NODES, 64, 0, stream>>>(fm, x2);
  // 3) distance + partial top-8 (4 j-chunks), then merge
  k_dist_topk<<<dim3(N_NODES / 64, 4), 256, 0, stream>>>(fm, x2, pv, pi);
  k_topk_merge<<<N_NODES / 256, 256, 0, stream>>>(pv, pi, tk);
  // 4) graph build
  hipMemsetAsync(deg, 0, N_NODES * 4, stream);
  hipMemsetAsync(cnt, 0, N_NODES * 4, stream);
  k_deg<<<E_TOT / 256, 256, 0, stream>>>(tk, deg);
  k_scan<<<1, 256, 0, stream>>>(deg, offs, dinv);
  k_fill<<<E_TOT / 256, 256, 0, stream>>>(tk, offs, cnt, insrc);
  k_sort<<<N_NODES / 256, 256, 0, stream>>>(offs, insrc);
  // 5) three GCN layers
  const float* Wl[3] = {W1, W2, W3};
  const float* bl[3] = {b1, b2, b3};
  for (int l = 0; l < 3; l++) {
    k_gemm<0><<<dim3(M_ROWS / 64, C_DIM / 64), 256, 0, stream>>>(
        X, Wl[l], nullptr, XW, M_ROWS, C_DIM, C_DIM);
    k_gcn_agg<<<M_ROWS, C_DIM, 0, stream>>>(XW, X, bl[l], dinv, offs, insrc);
  }
  // 6) MLP
  k_gemm<1><<<dim3(M_ROWS / 64, 3), 256, 0, stream>>>(X, U1, ub1, h1, M_ROWS, 192, C_DIM);
  k_gemm<1><<<dim3(M_ROWS / 64, 2), 256, 0, stream>>>(h1, U2, ub2, h2, M_ROWS, 96, 192);
  k_unc<<<M_ROWS / 256, 256, 0, stream>>>(h2, U3, ub3, unc);
  // 7) output
  size_t tot = (size_t)B_DIM * C_DIM * N_NODES;
  k_final<<<(tot + 255) / 256, 256, 0, stream>>>(fea, unc, out);
}

// Round 2
// 1519.280 us; speedup vs baseline: 1.2632x; 1.2632x over previous
//
#include <hip/hip_runtime.h>
#include <hip/hip_bf16.h>
#include <math.h>

#define N_NODES 4096
#define C_DIM   384
#define B_DIM   8
#define K_NB    8
#define E_TOT   (N_NODES * K_NB)     // 32768
#define M_ROWS  (B_DIM * N_NODES)    // 32768
#define NCHUNK  16

typedef unsigned long long u64;
#define KEY_INF 0xFFFFFFFFFFFFFFFFull

__device__ __forceinline__ void ce(u64& a, u64& b) {
  u64 lo = a < b ? a : b;
  u64 hi = a < b ? b : a;
  a = lo; b = hi;
}

// guarded static insertion into ascending sorted-8 list (registers only)
__device__ __forceinline__ void ins8(u64 key, u64 (&r)[8]) {
  if (key < r[7]) {
    #pragma unroll
    for (int i = 0; i < 8; i++) {
      u64 lo = key < r[i] ? key : r[i];
      u64 hi = key < r[i] ? r[i] : key;
      r[i] = lo; key = hi;
    }
  }
}

// merge two ascending sorted-8 lists -> ascending 8 smallest (static bitonic)
__device__ __forceinline__ void merge8(u64 (&r)[8], const u64 (&o)[8]) {
  u64 c[8];
  #pragma unroll
  for (int i = 0; i < 8; i++) c[i] = r[i] < o[7 - i] ? r[i] : o[7 - i];
  ce(c[0], c[4]); ce(c[1], c[5]); ce(c[2], c[6]); ce(c[3], c[7]);
  ce(c[0], c[2]); ce(c[1], c[3]); ce(c[4], c[6]); ce(c[5], c[7]);
  ce(c[0], c[1]); ce(c[2], c[3]); ce(c[4], c[5]); ce(c[6], c[7]);
  #pragma unroll
  for (int i = 0; i < 8; i++) r[i] = c[i];
}

// ---------------- transpose + batch mean ----------------
__global__ __launch_bounds__(256) void k_transpose_mean(
    const float* __restrict__ fea, float* __restrict__ X, float* __restrict__ fm) {
  __shared__ float t[32][33];
  __shared__ float acc[32][33];
  int n0 = blockIdx.x * 32, c0 = blockIdx.y * 32;
  int tx = threadIdx.x, ty = threadIdx.y;   // (32,8)
  for (int i = ty; i < 32; i += 8) acc[i][tx] = 0.0f;
  __syncthreads();
  for (int b = 0; b < B_DIM; b++) {
    for (int i = ty; i < 32; i += 8) {
      float v = fea[((size_t)b * C_DIM + (c0 + i)) * N_NODES + n0 + tx];
      t[i][tx] = v;
      acc[i][tx] += v;
    }
    __syncthreads();
    for (int i = ty; i < 32; i += 8)
      X[((size_t)b * N_NODES + (n0 + i)) * C_DIM + c0 + tx] = t[tx][i];
    __syncthreads();
  }
  for (int i = ty; i < 32; i += 8)
    fm[(size_t)(n0 + i) * C_DIM + c0 + tx] = acc[tx][i] * 0.125f;
}

// ---------------- squared norms ----------------
__global__ __launch_bounds__(64) void k_x2(const float* __restrict__ fm,
                                           float* __restrict__ x2) {
  int n = blockIdx.x;
  int lane = threadIdx.x;
  const float* r = fm + (size_t)n * C_DIM;
  float s = 0.0f;
  for (int c = lane; c < C_DIM; c += 64) s += r[c] * r[c];
  for (int d = 32; d > 0; d >>= 1) s += __shfl_down(s, d);
  if (lane == 0) x2[n] = s;
}

// ---------------- fused distance GEMM + register top-8 ----------------
// grid (64 i-tiles, 16 j-chunks of 256 cols). Per-thread: 4 rows x 4 cols.
__global__ __launch_bounds__(256) void k_dist_topk(
    const float* __restrict__ fm, const float* __restrict__ x2,
    u64* __restrict__ pk) {
  __shared__ float As[16][65];
  __shared__ float Bs[16][65];
  int i0 = blockIdx.x * 64;
  int jc = blockIdx.y;
  int jbeg = jc * 256;
  int t = threadIdx.x;
  int tx = t & 15, ty = t >> 4;

  u64 top[4][8];
  #pragma unroll
  for (int r = 0; r < 4; r++)
    #pragma unroll
    for (int q = 0; q < 8; q++) top[r][q] = KEY_INF;

  float x2i[4]; int iy[4], ix[4];
  #pragma unroll
  for (int r = 0; r < 4; r++) {
    int i = i0 + ty * 4 + r;
    x2i[r] = x2[i];
    iy[r] = i >> 6; ix[r] = i & 63;
  }

  for (int j0 = jbeg; j0 < jbeg + 256; j0 += 64) {
    float accv[4][4] = {};
    for (int cc = 0; cc < C_DIM; cc += 16) {
      __syncthreads();
      int kk = t & 15, ii = t >> 4;
      #pragma unroll
      for (int e = 0; e < 4; e++)
        As[kk][ii + e * 16] = fm[(size_t)(i0 + ii + e * 16) * C_DIM + cc + kk];
      #pragma unroll
      for (int e = 0; e < 4; e++)
        Bs[kk][ii + e * 16] = fm[(size_t)(j0 + ii + e * 16) * C_DIM + cc + kk];
      __syncthreads();
      #pragma unroll
      for (int kk2 = 0; kk2 < 16; kk2++) {
        float a[4], b[4];
        #pragma unroll
        for (int r = 0; r < 4; r++) a[r] = As[kk2][ty * 4 + r];
        #pragma unroll
        for (int s = 0; s < 4; s++) b[s] = Bs[kk2][tx * 4 + s];
        #pragma unroll
        for (int r = 0; r < 4; r++)
          #pragma unroll
          for (int s = 0; s < 4; s++) accv[r][s] += a[r] * b[s];
      }
    }
    // distances + guarded register insertion (ascending j order -> stable)
    #pragma unroll
    for (int s = 0; s < 4; s++) {
      int j = j0 + tx * 4 + s;
      float x2j = x2[j];
      int jy = j >> 6, jx = j & 63;
      #pragma unroll
      for (int r = 0; r < 4; r++) {
        float d2 = x2i[r] + x2j - 2.0f * accv[r][s];
        float fd = sqrtf(fmaxf(d2, 0.0f));
        float dy = (float)(iy[r] - jy), dx = (float)(ix[r] - jx);
        float sd = sqrtf(dy * dy + dx * dx);
        float comb = 0.7f * sd + 0.3f * fd;
        u64 key = ((u64)__float_as_uint(comb) << 12) | (u64)j;
        ins8(key, top[r]);
      }
    }
  }
  // butterfly merge across the 16 lanes sharing each row group (same wave)
  #pragma unroll
  for (int d = 1; d < 16; d <<= 1) {
    #pragma unroll
    for (int r = 0; r < 4; r++) {
      u64 o[8];
      #pragma unroll
      for (int q = 0; q < 8; q++) o[q] = __shfl_xor(top[r][q], d);
      merge8(top[r], o);
    }
  }
  if (tx == 0) {
    #pragma unroll
    for (int r = 0; r < 4; r++) {
      int i = i0 + ty * 4 + r;
      #pragma unroll
      for (int q = 0; q < 8; q++)
        pk[((size_t)jc * N_NODES + i) * 8 + q] = top[r][q];
    }
  }
}

// ---------------- merge 16 partial sorted lists + degree count ----------------
__global__ __launch_bounds__(256) void k_topk_merge(
    const u64* __restrict__ pk, int* __restrict__ tk, int* __restrict__ deg) {
  int n = blockIdx.x * 256 + threadIdx.x;
  if (n >= N_NODES) return;
  u64 r[8];
  #pragma unroll
  for (int q = 0; q < 8; q++) r[q] = KEY_INF;
  for (int c = 0; c < NCHUNK; c++) {
    const u64* lst = pk + ((size_t)c * N_NODES + n) * 8;
    #pragma unroll
    for (int q = 0; q < 8; q++) {
      u64 key = lst[q];
      if (key >= r[7]) break;   // ascending list: rest are larger
      ins8(key, r);
    }
  }
  #pragma unroll
  for (int o = 0; o < 8; o++) {
    int idx = (int)(r[o] & 0xFFF);
    tk[n * 8 + o] = idx;
    atomicAdd(&deg[idx], 1);
  }
}

// ---------------- exclusive scan (4096) + dinv ----------------
__global__ __launch_bounds__(256) void k_scan(const int* __restrict__ deg,
                                              int* __restrict__ offs,
                                              float* __restrict__ dinv) {
  __shared__ int ps[256];
  int t = threadIdx.x;
  int base = t * 16;
  int loc[16]; int s = 0;
  for (int i = 0; i < 16; i++) { int d = deg[base + i]; loc[i] = s; s += d; }
  ps[t] = s;
  __syncthreads();
  for (int d = 1; d < 256; d <<= 1) {
    int add = (t >= d) ? ps[t - d] : 0;
    __syncthreads();
    ps[t] += add;
    __syncthreads();
  }
  int cbase = (t == 0) ? 0 : ps[t - 1];
  for (int i = 0; i < 16; i++) offs[base + i] = cbase + loc[i];
  if (t == 255) offs[N_NODES] = ps[255];
  for (int i = 0; i < 16; i++)
    dinv[base + i] = 1.0f / sqrtf((float)deg[base + i]);
}

// ---------------- CSR fill ----------------
__global__ __launch_bounds__(256) void k_fill(const int* __restrict__ tk,
                                              const int* __restrict__ offs,
                                              int* __restrict__ cnt,
                                              int* __restrict__ insrc) {
  int e = blockIdx.x * 256 + threadIdx.x;
  if (e >= E_TOT) return;
  int i = e >> 3;
  int n = tk[e];
  int pos = offs[n] + atomicAdd(&cnt[n], 1);
  insrc[pos] = i;
}

// ---------------- per-node sort (determinism) ----------------
__global__ __launch_bounds__(256) void k_sort(const int* __restrict__ offs,
                                              int* __restrict__ insrc) {
  int n = blockIdx.x * 256 + threadIdx.x;
  if (n >= N_NODES) return;
  int beg = offs[n], end = offs[n + 1];
  for (int a = beg + 1; a < end; a++) {
    int v = insrc[a]; int p = a;
    while (p > beg && insrc[p - 1] > v) { insrc[p] = insrc[p - 1]; p--; }
    insrc[p] = v;
  }
}

// ---------------- generic fp32 GEMM + epilogue ----------------
__device__ __forceinline__ float gelu_f(float x) {
  const float k0 = 0.7978845608028654f;  // sqrt(2/pi)
  float x3 = x * x * x;
  return 0.5f * x * (1.0f + tanhf(k0 * (x + 0.044715f * x3)));
}

template <int EPI>  // 0 = none, 1 = bias+gelu
__global__ __launch_bounds__(256) void k_gemm(
    const float* __restrict__ A, const float* __restrict__ B,
    const float* __restrict__ bias, float* __restrict__ C,
    int M, int N, int K) {
  __shared__ float As[16][65];
  __shared__ float Bs[16][65];
  int m0 = blockIdx.x * 64, n0 = blockIdx.y * 64;
  int t = threadIdx.x, tx = t & 15, ty = t >> 4;
  float acc[4][4] = {};
  for (int cc = 0; cc < K; cc += 16) {
    __syncthreads();
    {
      int kk = t & 15, ii = t >> 4;
      #pragma unroll
      for (int e = 0; e < 4; e++)
        As[kk][ii + e * 16] = A[(size_t)(m0 + ii + e * 16) * K + cc + kk];
      int jj2 = t & 63, kr = t >> 6;
      #pragma unroll
      for (int e = 0; e < 4; e++) {
        int kk2 = kr * 4 + e;
        int col = n0 + jj2;
        Bs[kk2][jj2] = (col < N) ? B[(size_t)(cc + kk2) * N + col] : 0.0f;
      }
    }
    __syncthreads();
    #pragma unroll
    for (int kk = 0; kk < 16; kk++) {
      float a[4], b[4];
      #pragma unroll
      for (int r = 0; r < 4; r++) a[r] = As[kk][ty * 4 + r];
      #pragma unroll
      for (int s = 0; s < 4; s++) b[s] = Bs[kk][tx * 4 + s];
      #pragma unroll
      for (int r = 0; r < 4; r++)
        #pragma unroll
        for (int s = 0; s < 4; s++) acc[r][s] += a[r] * b[s];
    }
  }
  #pragma unroll
  for (int r = 0; r < 4; r++) {
    int m = m0 + ty * 4 + r;
    #pragma unroll
    for (int s = 0; s < 4; s++) {
      int n = n0 + tx * 4 + s;
      if (n < N) {
        float v = acc[r][s];
        if (EPI == 1) { v += bias[n]; v = gelu_f(v); }
        C[(size_t)m * N + n] = v;
      }
    }
  }
}

// ---------------- GCN aggregation: X += relu(dinv[n]*sum + bias) ----------------
__global__ __launch_bounds__(384) void k_gcn_agg(
    const float* __restrict__ xw, float* __restrict__ X,
    const float* __restrict__ bias, const float* __restrict__ dinv,
    const int* __restrict__ offs, const int* __restrict__ insrc) {
  int bn = blockIdx.x;          // b*4096 + n
  int b = bn >> 12, n = bn & 4095;
  int c = threadIdx.x;          // 384
  int beg = offs[n], end = offs[n + 1];
  const float* xwb = xw + (size_t)b * N_NODES * C_DIM;
  float s = 0.0f;
  for (int e = beg; e < end; e++) {
    int i = insrc[e];
    s += dinv[i] * xwb[(size_t)i * C_DIM + c];
  }
  float v = dinv[n] * s + bias[c];
  size_t o = (size_t)bn * C_DIM + c;
  X[o] += fmaxf(v, 0.0f);
}

// ---------------- final matvec (96 -> 1) + sigmoid ----------------
__global__ __launch_bounds__(256) void k_unc(
    const float* __restrict__ h2, const float* __restrict__ U3,
    const float* __restrict__ ub3, float* __restrict__ unc) {
  int r = blockIdx.x * 256 + threadIdx.x;
  if (r >= M_ROWS) return;
  const float* h = h2 + (size_t)r * 96;
  float s = 0.0f;
  #pragma unroll
  for (int c = 0; c < 96; c++) s += h[c] * U3[c];
  s += ub3[0];
  unc[r] = 1.0f / (1.0f + expf(-s));
}

// ---------------- out = fea * (1 + unc) ----------------
__global__ __launch_bounds__(256) void k_final(
    const float* __restrict__ fea, const float* __restrict__ unc,
    float* __restrict__ out) {
  size_t idx = (size_t)blockIdx.x * 256 + threadIdx.x;
  if (idx >= (size_t)B_DIM * C_DIM * N_NODES) return;
  int b = (int)(idx / ((size_t)C_DIM * N_NODES));
  int n = (int)(idx & (N_NODES - 1));
  out[idx] = fea[idx] * (1.0f + unc[(size_t)b * N_NODES + n]);
}

extern "C" void kernel_launch(void* const* d_in, const int* in_sizes, int n_in,
                              void* d_out, int out_size, void* d_ws, size_t ws_size,
                              hipStream_t stream) {
  const float* fea = (const float*)d_in[0];
  const float* W1  = (const float*)d_in[1];
  const float* b1  = (const float*)d_in[2];
  const float* W2  = (const float*)d_in[3];
  const float* b2  = (const float*)d_in[4];
  const float* W3  = (const float*)d_in[5];
  const float* b3  = (const float*)d_in[6];
  const float* U1  = (const float*)d_in[7];
  const float* ub1 = (const float*)d_in[8];
  const float* U2  = (const float*)d_in[9];
  const float* ub2 = (const float*)d_in[10];
  const float* U3  = (const float*)d_in[11];
  const float* ub3 = (const float*)d_in[12];
  float* out = (float*)d_out;

  char* ws = (char*)d_ws;
  const size_t SZ_X  = (size_t)M_ROWS * C_DIM * 4;        // 50331648
  float* X    = (float*)(ws);
  float* XW   = (float*)(ws + SZ_X);
  float* fm   = (float*)(ws + 2 * SZ_X);                  // 6291456
  float* x2   = (float*)(ws + 2 * SZ_X + 6291456);        // 16384
  int*   tk   = (int*)  (ws + 2 * SZ_X + 6307840);        // 131072
  int*   deg  = (int*)  (ws + 2 * SZ_X + 6438912);        // 16384
  float* dinv = (float*)(ws + 2 * SZ_X + 6455296);        // 16384
  int*   offs = (int*)  (ws + 2 * SZ_X + 6471680);        // 16640 (pad to 16896)
  int*   cnt  = (int*)  (ws + 2 * SZ_X + 6488576);        // 16384
  int*   insrc= (int*)  (ws + 2 * SZ_X + 6504960);        // 131072
  float* unc  = (float*)(ws + 2 * SZ_X + 6636032);        // 131072
  u64*   pk   = (u64*)  (ws + 2 * SZ_X + 6767104);        // 16*4096*8*8 = 4194304
  float* h1   = XW;                                       // [32768,192]
  float* h2   = (float*)(ws + SZ_X + (size_t)M_ROWS * 192 * 4); // [32768,96]

  // 1) transpose + mean
  k_transpose_mean<<<dim3(N_NODES / 32, C_DIM / 32), dim3(32, 8), 0, stream>>>(fea, X, fm);
  // 2) norms
  k_x2<<<N_NODES, 64, 0, stream>>>(fm, x2);
  // 3) distance + register top-8 (16 j-chunks), then merge (+deg)
  hipMemsetAsync(deg, 0, N_NODES * 4, stream);
  hipMemsetAsync(cnt, 0, N_NODES * 4, stream);
  k_dist_topk<<<dim3(N_NODES / 64, NCHUNK), 256, 0, stream>>>(fm, x2, pk);
  k_topk_merge<<<N_NODES / 256, 256, 0, stream>>>(pk, tk, deg);
  // 4) graph build
  k_scan<<<1, 256, 0, stream>>>(deg, offs, dinv);
  k_fill<<<E_TOT / 256, 256, 0, stream>>>(tk, offs, cnt, insrc);
  k_sort<<<N_NODES / 256, 256, 0, stream>>>(offs, insrc);
  // 5) three GCN layers
  const float* Wl[3] = {W1, W2, W3};
  const float* bl[3] = {b1, b2, b3};
  for (int l = 0; l < 3; l++) {
    k_gemm<0><<<dim3(M_ROWS / 64, C_DIM / 64), 256, 0, stream>>>(
        X, Wl[l], nullptr, XW, M_ROWS, C_DIM, C_DIM);
    k_gcn_agg<<<M_ROWS, C_DIM, 0, stream>>>(XW, X, bl[l], dinv, offs, insrc);
  }
  // 6) MLP
  k_gemm<1><<<dim3(M_ROWS / 64, 3), 256, 0, stream>>>(X, U1, ub1, h1, M_ROWS, 192, C_DIM);
  k_gemm<1><<<dim3(M_ROWS / 64, 2), 256, 0, stream>>>(h1, U2, ub2, h2, M_ROWS, 96, 192);
  k_unc<<<M_ROWS / 256, 256, 0, stream>>>(h2, U3, ub3, unc);
  // 7) output
  size_t tot = (size_t)B_DIM * C_DIM * N_NODES;
  k_final<<<(tot + 255) / 256, 256, 0, stream>>>(fea, unc, out);
}

// Round 3
// 881.893 us; speedup vs baseline: 2.1761x; 1.7227x over previous
//
#include <hip/hip_runtime.h>
#include <hip/hip_bf16.h>
#include <math.h>

#define N_NODES 4096
#define C_DIM   384
#define B_DIM   8
#define K_NB    8
#define E_TOT   (N_NODES * K_NB)     // 32768
#define M_ROWS  (B_DIM * N_NODES)    // 32768
#define NCHUNK  32                   // j-chunks of 128 cols

typedef unsigned long long u64;
typedef unsigned short u16;
typedef __attribute__((ext_vector_type(8))) short bf16x8;
typedef __attribute__((ext_vector_type(4))) float f32x4;
#define KEY_INF 0xFFFFFFFFFFFFFFFFull

__device__ __forceinline__ u16 f2bf(float f) {
  unsigned u = __float_as_uint(f);
  u += 0x7FFFu + ((u >> 16) & 1u);
  return (u16)(u >> 16);
}
__device__ __forceinline__ float bf2f(u16 h) {
  return __uint_as_float((unsigned)h << 16);
}
__device__ __forceinline__ f32x4 mfma16(bf16x8 a, bf16x8 b, f32x4 c) {
  return __builtin_amdgcn_mfma_f32_16x16x32_bf16(a, b, c, 0, 0, 0);
}

__device__ __forceinline__ void ce(u64& a, u64& b) {
  u64 lo = a < b ? a : b;
  u64 hi = a < b ? b : a;
  a = lo; b = hi;
}
__device__ __forceinline__ void ins8(u64 key, u64 (&r)[8]) {
  if (key < r[7]) {
    #pragma unroll
    for (int i = 0; i < 8; i++) {
      u64 lo = key < r[i] ? key : r[i];
      u64 hi = key < r[i] ? r[i] : key;
      r[i] = lo; key = hi;
    }
  }
}
__device__ __forceinline__ void merge8(u64 (&r)[8], const u64 (&o)[8]) {
  u64 c[8];
  #pragma unroll
  for (int i = 0; i < 8; i++) c[i] = r[i] < o[7 - i] ? r[i] : o[7 - i];
  ce(c[0], c[4]); ce(c[1], c[5]); ce(c[2], c[6]); ce(c[3], c[7]);
  ce(c[0], c[2]); ce(c[1], c[3]); ce(c[4], c[6]); ce(c[5], c[7]);
  ce(c[0], c[1]); ce(c[2], c[3]); ce(c[4], c[5]); ce(c[6], c[7]);
  #pragma unroll
  for (int i = 0; i < 8; i++) r[i] = c[i];
}

// ---------------- weight prep: transpose + bf16 ----------------
__global__ __launch_bounds__(256) void k_prep_w(
    const float* __restrict__ W1, const float* __restrict__ W2,
    const float* __restrict__ W3, const float* __restrict__ U1,
    const float* __restrict__ U2,
    u16* __restrict__ Wt1, u16* __restrict__ Wt2, u16* __restrict__ Wt3,
    u16* __restrict__ U1t, u16* __restrict__ U2t) {
  int idx = blockIdx.x * 256 + threadIdx.x;
  if (idx < 147456) {
    int n = idx / 384, k = idx % 384;
    Wt1[idx] = f2bf(W1[k * 384 + n]);
  } else if (idx < 294912) {
    int i = idx - 147456; int n = i / 384, k = i % 384;
    Wt2[i] = f2bf(W2[k * 384 + n]);
  } else if (idx < 442368) {
    int i = idx - 294912; int n = i / 384, k = i % 384;
    Wt3[i] = f2bf(W3[k * 384 + n]);
  } else if (idx < 516096) {
    int i = idx - 442368; int n = i / 384, k = i % 384;
    U1t[i] = f2bf(U1[k * 192 + n]);
  } else if (idx < 534528) {
    int i = idx - 516096; int n = i / 192, k = i % 192;
    U2t[i] = f2bf(U2[k * 96 + n]);
  }
}

// ---------------- transpose + batch mean (+ bf16 splits) ----------------
__global__ __launch_bounds__(256) void k_transpose_mean(
    const float* __restrict__ fea, float* __restrict__ X, u16* __restrict__ Xb,
    u16* __restrict__ fh, u16* __restrict__ fl) {
  __shared__ float tt[32][33];
  __shared__ float ac[32][33];
  int n0 = blockIdx.x * 32, c0 = blockIdx.y * 32;
  int tx = threadIdx.x, ty = threadIdx.y;   // (32,8)
  for (int i = ty; i < 32; i += 8) ac[i][tx] = 0.0f;
  __syncthreads();
  for (int b = 0; b < B_DIM; b++) {
    for (int i = ty; i < 32; i += 8) {
      float v = fea[((size_t)b * C_DIM + (c0 + i)) * N_NODES + n0 + tx];
      tt[i][tx] = v;
      ac[i][tx] += v;
    }
    __syncthreads();
    for (int i = ty; i < 32; i += 8) {
      float v = tt[tx][i];
      size_t o = ((size_t)b * N_NODES + (n0 + i)) * C_DIM + c0 + tx;
      X[o] = v;
      Xb[o] = f2bf(v);
    }
    __syncthreads();
  }
  for (int i = ty; i < 32; i += 8) {
    float m = ac[tx][i] * 0.125f;
    u16 h = f2bf(m);
    size_t o = (size_t)(n0 + i) * C_DIM + c0 + tx;
    fh[o] = h;
    fl[o] = f2bf(m - bf2f(h));
  }
}

// ---------------- squared norms (from hi+lo) ----------------
__global__ __launch_bounds__(64) void k_x2(const u16* __restrict__ fh,
                                           const u16* __restrict__ fl,
                                           float* __restrict__ x2) {
  int n = blockIdx.x;
  int lane = threadIdx.x;
  const u16* rh = fh + (size_t)n * C_DIM;
  const u16* rl = fl + (size_t)n * C_DIM;
  float s = 0.0f;
  for (int c = lane; c < C_DIM; c += 64) {
    float v = bf2f(rh[c]) + bf2f(rl[c]);
    s += v * v;
  }
  for (int d = 32; d > 0; d >>= 1) s += __shfl_down(s, d);
  if (lane == 0) x2[n] = s;
}

// ---------------- MFMA split-bf16 distance + register top-8 ----------------
// grid (64, 32): 64-row i-tile x 128-col j-chunk; 4 waves, wave w = 16 i-rows.
__global__ __launch_bounds__(256) void k_dist_topk(
    const u16* __restrict__ fh, const u16* __restrict__ fl,
    const float* __restrict__ x2, u64* __restrict__ pk) {
  int t = threadIdx.x;
  int lane = t & 63, w = t >> 6;
  int i0 = blockIdx.x * 64;
  int jbeg = blockIdx.y * 128;
  int arow = i0 + w * 16 + (lane & 15);
  int kb = (lane >> 4) * 8;

  f32x4 acc[8];
  #pragma unroll
  for (int jt = 0; jt < 8; jt++) acc[jt] = (f32x4){0.f, 0.f, 0.f, 0.f};

  const u16* ahp = fh + (size_t)arow * C_DIM + kb;
  const u16* alp = fl + (size_t)arow * C_DIM + kb;
  const u16* bhp[8];
  const u16* blp[8];
  int jrow0 = jbeg + (lane & 15);
  #pragma unroll
  for (int jt = 0; jt < 8; jt++) {
    bhp[jt] = fh + (size_t)(jrow0 + jt * 16) * C_DIM + kb;
    blp[jt] = fl + (size_t)(jrow0 + jt * 16) * C_DIM + kb;
  }

  #pragma unroll 2
  for (int kk = 0; kk < C_DIM; kk += 32) {
    bf16x8 ah = *(const bf16x8*)(ahp + kk);
    bf16x8 al = *(const bf16x8*)(alp + kk);
    #pragma unroll
    for (int jt = 0; jt < 8; jt++) {
      bf16x8 bh = *(const bf16x8*)(bhp[jt] + kk);
      bf16x8 bl = *(const bf16x8*)(blp[jt] + kk);
      acc[jt] = mfma16(ah, bh, acc[jt]);
      acc[jt] = mfma16(ah, bl, acc[jt]);
      acc[jt] = mfma16(al, bh, acc[jt]);
      acc[jt] = mfma16(al, bl, acc[jt]);
    }
  }

  // epilogue: distances + per-thread top-8 (rows = (lane>>4)*4+reg)
  u64 top[4][8];
  #pragma unroll
  for (int r = 0; r < 4; r++)
    #pragma unroll
    for (int q = 0; q < 8; q++) top[r][q] = KEY_INF;

  int ibase = i0 + w * 16 + ((lane >> 4) << 2);
  float x2i[4]; int iy[4], ix[4];
  #pragma unroll
  for (int r = 0; r < 4; r++) {
    int i = ibase + r;
    x2i[r] = x2[i];
    iy[r] = i >> 6; ix[r] = i & 63;
  }
  #pragma unroll
  for (int jt = 0; jt < 8; jt++) {
    int j = jbeg + jt * 16 + (lane & 15);
    float x2j = x2[j];
    int jy = j >> 6, jx = j & 63;
    #pragma unroll
    for (int r = 0; r < 4; r++) {
      float d2 = x2i[r] + x2j - 2.0f * acc[jt][r];
      float fd = sqrtf(fmaxf(d2, 0.0f));
      float dy = (float)(iy[r] - jy), dx = (float)(ix[r] - jx);
      float sd = sqrtf(dy * dy + dx * dx);
      float comb = 0.7f * sd + 0.3f * fd;
      u64 key = ((u64)__float_as_uint(comb) << 12) | (u64)j;
      ins8(key, top[r]);
    }
  }
  // butterfly merge across the 16 lanes sharing the same rows
  #pragma unroll
  for (int d = 1; d < 16; d <<= 1) {
    #pragma unroll
    for (int r = 0; r < 4; r++) {
      u64 o[8];
      #pragma unroll
      for (int q = 0; q < 8; q++) o[q] = __shfl_xor(top[r][q], d);
      merge8(top[r], o);
    }
  }
  if ((lane & 15) == 0) {
    #pragma unroll
    for (int r = 0; r < 4; r++) {
      int i = ibase + r;
      #pragma unroll
      for (int q = 0; q < 8; q++)
        pk[((size_t)blockIdx.y * N_NODES + i) * 8 + q] = top[r][q];
    }
  }
}

// ---------------- merge 32 partial sorted lists + degree count ----------------
__global__ __launch_bounds__(256) void k_topk_merge(
    const u64* __restrict__ pk, int* __restrict__ tk, int* __restrict__ deg) {
  int n = blockIdx.x * 256 + threadIdx.x;
  if (n >= N_NODES) return;
  u64 r[8];
  #pragma unroll
  for (int q = 0; q < 8; q++) r[q] = KEY_INF;
  for (int c = 0; c < NCHUNK; c++) {
    const u64* lst = pk + ((size_t)c * N_NODES + n) * 8;
    #pragma unroll
    for (int q = 0; q < 8; q++) {
      u64 key = lst[q];
      if (key >= r[7]) break;
      ins8(key, r);
    }
  }
  #pragma unroll
  for (int o = 0; o < 8; o++) {
    int idx = (int)(r[o] & 0xFFF);
    tk[n * 8 + o] = idx;
    atomicAdd(&deg[idx], 1);
  }
}

// ---------------- exclusive scan (4096) + dinv ----------------
__global__ __launch_bounds__(256) void k_scan(const int* __restrict__ deg,
                                              int* __restrict__ offs,
                                              float* __restrict__ dinv) {
  __shared__ int ps[256];
  int t = threadIdx.x;
  int base = t * 16;
  int loc[16]; int s = 0;
  for (int i = 0; i < 16; i++) { int d = deg[base + i]; loc[i] = s; s += d; }
  ps[t] = s;
  __syncthreads();
  for (int d = 1; d < 256; d <<= 1) {
    int add = (t >= d) ? ps[t - d] : 0;
    __syncthreads();
    ps[t] += add;
    __syncthreads();
  }
  int cbase = (t == 0) ? 0 : ps[t - 1];
  for (int i = 0; i < 16; i++) offs[base + i] = cbase + loc[i];
  if (t == 255) offs[N_NODES] = ps[255];
  for (int i = 0; i < 16; i++)
    dinv[base + i] = 1.0f / sqrtf((float)deg[base + i]);
}

// ---------------- CSR fill ----------------
__global__ __launch_bounds__(256) void k_fill(const int* __restrict__ tk,
                                              const int* __restrict__ offs,
                                              int* __restrict__ cnt,
                                              int* __restrict__ insrc) {
  int e = blockIdx.x * 256 + threadIdx.x;
  if (e >= E_TOT) return;
  int i = e >> 3;
  int n = tk[e];
  int pos = offs[n] + atomicAdd(&cnt[n], 1);
  insrc[pos] = i;
}

// ---------------- per-node sort (determinism) ----------------
__global__ __launch_bounds__(256) void k_sort(const int* __restrict__ offs,
                                              int* __restrict__ insrc) {
  int n = blockIdx.x * 256 + threadIdx.x;
  if (n >= N_NODES) return;
  int beg = offs[n], end = offs[n + 1];
  for (int a = beg + 1; a < end; a++) {
    int v = insrc[a]; int p = a;
    while (p > beg && insrc[p - 1] > v) { insrc[p] = insrc[p - 1]; p--; }
    insrc[p] = v;
  }
}

// ---------------- bf16 MFMA GEMM, no LDS ----------------
// C[M,N] = A[M,K](bf16) @ Bt[N,K](bf16)^T. block 256 = 4 waves; tile 128Mx64N.
// EPI: 1 = bias+gelu -> bf16 out, 2 = bias+gelu -> f32 out, 3 = plain -> bf16 out
__device__ __forceinline__ float gelu_f(float x) {
  const float k0 = 0.7978845608028654f;  // sqrt(2/pi)
  float x3 = x * x * x;
  return 0.5f * x * (1.0f + tanhf(k0 * (x + 0.044715f * x3)));
}

template <int EPI>
__global__ __launch_bounds__(256) void k_gemm_mfma(
    const u16* __restrict__ A, const u16* __restrict__ Bt,
    const float* __restrict__ bias, void* __restrict__ Cout,
    int M, int N, int K) {
  int t = threadIdx.x, lane = t & 63, w = t >> 6;
  int m0 = blockIdx.x * 128, n0 = blockIdx.y * 64;
  int kb = (lane >> 4) * 8;
  int ncol = n0 + (lane & 15);

  f32x4 acc[2][4];
  #pragma unroll
  for (int s = 0; s < 2; s++)
    #pragma unroll
    for (int nt = 0; nt < 4; nt++) acc[s][nt] = (f32x4){0.f, 0.f, 0.f, 0.f};

  const u16* a0p = A + (size_t)(m0 + w * 32 + (lane & 15)) * K + kb;
  const u16* a1p = a0p + (size_t)16 * K;
  const u16* bp[4];
  bool bv[4];
  #pragma unroll
  for (int nt = 0; nt < 4; nt++) {
    int nr = ncol + nt * 16;
    bv[nt] = (nr < N);
    bp[nt] = Bt + (size_t)(bv[nt] ? nr : 0) * K + kb;
  }

  for (int kk = 0; kk < K; kk += 32) {
    bf16x8 a0 = *(const bf16x8*)(a0p + kk);
    bf16x8 a1 = *(const bf16x8*)(a1p + kk);
    #pragma unroll
    for (int nt = 0; nt < 4; nt++) {
      bf16x8 b;
      if (bv[nt]) b = *(const bf16x8*)(bp[nt] + kk);
      else b = (bf16x8){0, 0, 0, 0, 0, 0, 0, 0};
      acc[0][nt] = mfma16(a0, b, acc[0][nt]);
      acc[1][nt] = mfma16(a1, b, acc[1][nt]);
    }
  }

  int rbase = m0 + w * 32 + ((lane >> 4) << 2);
  #pragma unroll
  for (int sub = 0; sub < 2; sub++) {
    #pragma unroll
    for (int nt = 0; nt < 4; nt++) {
      int n = n0 + nt * 16 + (lane & 15);
      if (n >= N) continue;
      #pragma unroll
      for (int r = 0; r < 4; r++) {
        int m = rbase + sub * 16 + r;
        float v = acc[sub][nt][r];
        if (EPI == 1 || EPI == 2) { v += bias[n]; v = gelu_f(v); }
        if (EPI == 1 || EPI == 3)
          ((u16*)Cout)[(size_t)m * N + n] = f2bf(v);
        else
          ((float*)Cout)[(size_t)m * N + n] = v;
      }
    }
  }
}

// ---------------- GCN aggregation: X += relu(dinv[n]*sum + bias), emit Xb ----------------
__global__ __launch_bounds__(384) void k_gcn_agg(
    const u16* __restrict__ xw, float* __restrict__ X, u16* __restrict__ Xb,
    const float* __restrict__ bias, const float* __restrict__ dinv,
    const int* __restrict__ offs, const int* __restrict__ insrc) {
  int bn = blockIdx.x;          // b*4096 + n
  int b = bn >> 12, n = bn & 4095;
  int c = threadIdx.x;          // 384
  int beg = offs[n], end = offs[n + 1];
  const u16* xwb = xw + (size_t)b * N_NODES * C_DIM;
  float s = 0.0f;
  for (int e = beg; e < end; e++) {
    int i = insrc[e];
    s += dinv[i] * bf2f(xwb[(size_t)i * C_DIM + c]);
  }
  float v = dinv[n] * s + bias[c];
  size_t o = (size_t)bn * C_DIM + c;
  float nx = X[o] + fmaxf(v, 0.0f);
  X[o] = nx;
  Xb[o] = f2bf(nx);
}

// ---------------- final matvec (96 -> 1) + sigmoid ----------------
__global__ __launch_bounds__(256) void k_unc(
    const float* __restrict__ h2, const float* __restrict__ U3,
    const float* __restrict__ ub3, float* __restrict__ unc) {
  int r = blockIdx.x * 256 + threadIdx.x;
  if (r >= M_ROWS) return;
  const float4* h = (const float4*)(h2 + (size_t)r * 96);
  float s = 0.0f;
  #pragma unroll
  for (int c = 0; c < 24; c++) {
    float4 v = h[c];
    const float4 u = *(const float4*)(U3 + c * 4);
    s += v.x * u.x + v.y * u.y + v.z * u.z + v.w * u.w;
  }
  s += ub3[0];
  unc[r] = 1.0f / (1.0f + expf(-s));
}

// ---------------- out = fea * (1 + unc) ----------------
__global__ __launch_bounds__(256) void k_final(
    const float* __restrict__ fea, const float* __restrict__ unc,
    float* __restrict__ out) {
  size_t idx = (size_t)blockIdx.x * 256 + threadIdx.x;
  if (idx >= (size_t)B_DIM * C_DIM * N_NODES) return;
  int b = (int)(idx / ((size_t)C_DIM * N_NODES));
  int n = (int)(idx & (N_NODES - 1));
  out[idx] = fea[idx] * (1.0f + unc[(size_t)b * N_NODES + n]);
}

extern "C" void kernel_launch(void* const* d_in, const int* in_sizes, int n_in,
                              void* d_out, int out_size, void* d_ws, size_t ws_size,
                              hipStream_t stream) {
  const float* fea = (const float*)d_in[0];
  const float* W1  = (const float*)d_in[1];
  const float* b1  = (const float*)d_in[2];
  const float* W2  = (const float*)d_in[3];
  const float* b2  = (const float*)d_in[4];
  const float* W3  = (const float*)d_in[5];
  const float* b3  = (const float*)d_in[6];
  const float* U1  = (const float*)d_in[7];
  const float* ub1 = (const float*)d_in[8];
  const float* U2  = (const float*)d_in[9];
  const float* ub2 = (const float*)d_in[10];
  const float* U3  = (const float*)d_in[11];
  const float* ub3 = (const float*)d_in[12];
  float* out = (float*)d_out;

  char* ws = (char*)d_ws;
  float* X    = (float*)(ws + 0);                       // 50331648
  u16*   Xb   = (u16*)  (ws + 50331648);                // 25165824
  u16*   XWb  = (u16*)  (ws + 75497472);                // 25165824
  u64*   pk   = (u64*)  (ws + 75497472);                // 8388608 (aliases XWb, pre-GEMM)
  u16*   h1b  = (u16*)  (ws + 75497472);                // 12582912 (aliases XWb, post-GCN)
  float* h2   = (float*)(ws + 75497472 + 12582912);     // 12582912
  u16*   fh   = (u16*)  (ws + 100663296);               // 3145728
  u16*   fl   = (u16*)  (ws + 103809024);               // 3145728
  float* x2   = (float*)(ws + 106954752);               // 16384
  int*   tk   = (int*)  (ws + 106971136);               // 131072
  int*   deg  = (int*)  (ws + 107102208);               // 16384
  float* dinv = (float*)(ws + 107118592);               // 16384
  int*   offs = (int*)  (ws + 107134976);               // 16896
  int*   cnt  = (int*)  (ws + 107151872);               // 16384
  int*   insrc= (int*)  (ws + 107168256);               // 131072
  float* unc  = (float*)(ws + 107299328);               // 131072
  u16*   Wt1  = (u16*)  (ws + 107430400);               // 294912
  u16*   Wt2  = (u16*)  (ws + 107725312);               // 294912
  u16*   Wt3  = (u16*)  (ws + 108020224);               // 294912
  u16*   U1t  = (u16*)  (ws + 108315136);               // 147456
  u16*   U2t  = (u16*)  (ws + 108462592);               // 36864

  // 0) weights -> transposed bf16
  k_prep_w<<<2088, 256, 0, stream>>>(W1, W2, W3, U1, U2, Wt1, Wt2, Wt3, U1t, U2t);
  // 1) transpose + mean (+ bf16)
  k_transpose_mean<<<dim3(N_NODES / 32, C_DIM / 32), dim3(32, 8), 0, stream>>>(
      fea, X, Xb, fh, fl);
  // 2) norms
  k_x2<<<N_NODES, 64, 0, stream>>>(fh, fl, x2);
  // 3) distance (split-bf16 MFMA) + register top-8, then merge (+deg)
  hipMemsetAsync(deg, 0, N_NODES * 4, stream);
  hipMemsetAsync(cnt, 0, N_NODES * 4, stream);
  k_dist_topk<<<dim3(N_NODES / 64, NCHUNK), 256, 0, stream>>>(fh, fl, x2, pk);
  k_topk_merge<<<N_NODES / 256, 256, 0, stream>>>(pk, tk, deg);
  // 4) graph build
  k_scan<<<1, 256, 0, stream>>>(deg, offs, dinv);
  k_fill<<<E_TOT / 256, 256, 0, stream>>>(tk, offs, cnt, insrc);
  k_sort<<<N_NODES / 256, 256, 0, stream>>>(offs, insrc);
  // 5) three GCN layers (bf16 MFMA GEMM + aggregation)
  const u16* Wl[3] = {Wt1, Wt2, Wt3};
  const float* bl[3] = {b1, b2, b3};
  for (int l = 0; l < 3; l++) {
    k_gemm_mfma<3><<<dim3(M_ROWS / 128, C_DIM / 64), 256, 0, stream>>>(
        Xb, Wl[l], nullptr, XWb, M_ROWS, C_DIM, C_DIM);
    k_gcn_agg<<<M_ROWS, C_DIM, 0, stream>>>(XWb, X, Xb, bl[l], dinv, offs, insrc);
  }
  // 6) MLP
  k_gemm_mfma<1><<<dim3(M_ROWS / 128, 3), 256, 0, stream>>>(
      Xb, U1t, ub1, h1b, M_ROWS, 192, C_DIM);
  k_gemm_mfma<2><<<dim3(M_ROWS / 128, 2), 256, 0, stream>>>(
      h1b, U2t, ub2, h2, M_ROWS, 96, 192);
  k_unc<<<M_ROWS / 256, 256, 0, stream>>>(h2, U3, ub3, unc);
  // 7) output
  size_t tot = (size_t)B_DIM * C_DIM * N_NODES;
  k_final<<<(tot + 255) / 256, 256, 0, stream>>>(fea, unc, out);
}

// Round 4
// 591.009 us; speedup vs baseline: 3.2472x; 1.4922x over previous
//
#include <hip/hip_runtime.h>
#include <hip/hip_bf16.h>
#include <math.h>

#define N_NODES 4096
#define C_DIM   384
#define B_DIM   8
#define K_NB    8
#define E_TOT   (N_NODES * K_NB)     // 32768
#define M_ROWS  (B_DIM * N_NODES)    // 32768
#define NCHUNK  32                   // j-chunks of 128 cols

typedef unsigned long long u64;
typedef unsigned short u16;
typedef __attribute__((ext_vector_type(8))) short bf16x8;
typedef __attribute__((ext_vector_type(4))) float f32x4;
#define KEY_INF 0xFFFFFFFFFFFFFFFFull

__device__ __forceinline__ u16 f2bf(float f) {
  unsigned u = __float_as_uint(f);
  u += 0x7FFFu + ((u >> 16) & 1u);
  return (u16)(u >> 16);
}
__device__ __forceinline__ float bf2f(u16 h) {
  return __uint_as_float((unsigned)h << 16);
}
__device__ __forceinline__ f32x4 mfma16(bf16x8 a, bf16x8 b, f32x4 c) {
  return __builtin_amdgcn_mfma_f32_16x16x32_bf16(a, b, c, 0, 0, 0);
}

__device__ __forceinline__ void ce(u64& a, u64& b) {
  u64 lo = a < b ? a : b;
  u64 hi = a < b ? b : a;
  a = lo; b = hi;
}
// Batcher odd-even mergesort for 8 (19 comparators, branchless)
__device__ __forceinline__ void sort8(u64 (&k)[8]) {
  ce(k[0],k[1]); ce(k[2],k[3]); ce(k[4],k[5]); ce(k[6],k[7]);
  ce(k[0],k[2]); ce(k[1],k[3]); ce(k[4],k[6]); ce(k[5],k[7]);
  ce(k[1],k[2]); ce(k[5],k[6]);
  ce(k[0],k[4]); ce(k[1],k[5]); ce(k[2],k[6]); ce(k[3],k[7]);
  ce(k[2],k[4]); ce(k[3],k[5]);
  ce(k[1],k[2]); ce(k[3],k[4]); ce(k[5],k[6]);
}
__device__ __forceinline__ void ins8(u64 key, u64 (&r)[8]) {
  if (key < r[7]) {
    #pragma unroll
    for (int i = 0; i < 8; i++) {
      u64 lo = key < r[i] ? key : r[i];
      u64 hi = key < r[i] ? r[i] : key;
      r[i] = lo; key = hi;
    }
  }
}
// merge two ascending sorted-8 lists -> ascending 8 smallest
__device__ __forceinline__ void merge8(u64 (&r)[8], const u64 (&o)[8]) {
  u64 c[8];
  #pragma unroll
  for (int i = 0; i < 8; i++) c[i] = r[i] < o[7 - i] ? r[i] : o[7 - i];
  ce(c[0], c[4]); ce(c[1], c[5]); ce(c[2], c[6]); ce(c[3], c[7]);
  ce(c[0], c[2]); ce(c[1], c[3]); ce(c[4], c[6]); ce(c[5], c[7]);
  ce(c[0], c[1]); ce(c[2], c[3]); ce(c[4], c[5]); ce(c[6], c[7]);
  #pragma unroll
  for (int i = 0; i < 8; i++) r[i] = c[i];
}

// ---------------- weight prep: transpose + bf16 ----------------
__global__ __launch_bounds__(256) void k_prep_w(
    const float* __restrict__ W1, const float* __restrict__ W2,
    const float* __restrict__ W3, const float* __restrict__ U1,
    const float* __restrict__ U2,
    u16* __restrict__ Wt1, u16* __restrict__ Wt2, u16* __restrict__ Wt3,
    u16* __restrict__ U1t, u16* __restrict__ U2t) {
  int idx = blockIdx.x * 256 + threadIdx.x;
  if (idx < 147456) {
    int n = idx / 384, k = idx % 384;
    Wt1[idx] = f2bf(W1[k * 384 + n]);
  } else if (idx < 294912) {
    int i = idx - 147456; int n = i / 384, k = i % 384;
    Wt2[i] = f2bf(W2[k * 384 + n]);
  } else if (idx < 442368) {
    int i = idx - 294912; int n = i / 384, k = i % 384;
    Wt3[i] = f2bf(W3[k * 384 + n]);
  } else if (idx < 516096) {
    int i = idx - 442368; int n = i / 384, k = i % 384;
    U1t[i] = f2bf(U1[k * 192 + n]);
  } else if (idx < 534528) {
    int i = idx - 516096; int n = i / 192, k = i % 192;
    U2t[i] = f2bf(U2[k * 96 + n]);
  }
}

// ---------------- transpose + batch mean (+ bf16 splits), float4 reads ----------------
__global__ __launch_bounds__(256) void k_transpose_mean(
    const float* __restrict__ fea, float* __restrict__ X, u16* __restrict__ Xb,
    u16* __restrict__ fh, u16* __restrict__ fl) {
  __shared__ float tb[32][132];
  __shared__ float ac[32][132];
  int n0 = blockIdx.x * 128, c0 = blockIdx.y * 32;
  int tx = threadIdx.x, ty = threadIdx.y;   // (32,8)
  for (int i = ty; i < 32; i += 8) {
    #pragma unroll
    for (int e = 0; e < 4; e++) ac[i][tx * 4 + e] = 0.0f;
  }
  __syncthreads();
  for (int b = 0; b < B_DIM; b++) {
    for (int i = ty; i < 32; i += 8) {
      float4 v = *(const float4*)(fea +
          ((size_t)b * C_DIM + (c0 + i)) * N_NODES + n0 + tx * 4);
      *(float4*)&tb[i][tx * 4] = v;
      ac[i][tx * 4 + 0] += v.x;
      ac[i][tx * 4 + 1] += v.y;
      ac[i][tx * 4 + 2] += v.z;
      ac[i][tx * 4 + 3] += v.w;
    }
    __syncthreads();
    for (int rr = ty; rr < 128; rr += 8) {
      float v = tb[tx][rr];
      size_t o = ((size_t)b * N_NODES + (n0 + rr)) * C_DIM + c0 + tx;
      X[o] = v;
      Xb[o] = f2bf(v);
    }
    __syncthreads();
  }
  for (int rr = ty; rr < 128; rr += 8) {
    float m = ac[tx][rr] * 0.125f;
    u16 h = f2bf(m);
    size_t o = (size_t)(n0 + rr) * C_DIM + c0 + tx;
    fh[o] = h;
    fl[o] = f2bf(m - bf2f(h));
  }
}

// ---------------- squared norms (from hi+lo) ----------------
__global__ __launch_bounds__(64) void k_x2(const u16* __restrict__ fh,
                                           const u16* __restrict__ fl,
                                           float* __restrict__ x2) {
  int n = blockIdx.x;
  int lane = threadIdx.x;
  const u16* rh = fh + (size_t)n * C_DIM;
  const u16* rl = fl + (size_t)n * C_DIM;
  float s = 0.0f;
  for (int c = lane; c < C_DIM; c += 64) {
    float v = bf2f(rh[c]) + bf2f(rl[c]);
    s += v * v;
  }
  for (int d = 32; d > 0; d >>= 1) s += __shfl_down(s, d);
  if (lane == 0) x2[n] = s;
}

// ---------------- MFMA 3-term split-bf16 distance + register top-8 ----------------
// grid (32, 32): 128-row i-tile x 128-col j-chunk; 4 waves, wave = 32 i-rows.
__global__ __launch_bounds__(256) void k_dist_topk(
    const u16* __restrict__ fh, const u16* __restrict__ fl,
    const float* __restrict__ x2, u64* __restrict__ pk) {
  int t = threadIdx.x;
  int lane = t & 63, w = t >> 6;
  int i0 = blockIdx.x * 128 + w * 32;
  int jbeg = blockIdx.y * 128;
  int l15 = lane & 15;
  int kb = (lane >> 4) * 8;
  const size_t R16 = (size_t)16 * C_DIM;

  f32x4 acc[2][8];
  #pragma unroll
  for (int s = 0; s < 2; s++)
    #pragma unroll
    for (int jt = 0; jt < 8; jt++) acc[s][jt] = (f32x4){0.f, 0.f, 0.f, 0.f};

  const u16* ah = fh + (size_t)(i0 + l15) * C_DIM + kb;
  const u16* al = fl + (size_t)(i0 + l15) * C_DIM + kb;
  const u16* bh = fh + (size_t)(jbeg + l15) * C_DIM + kb;
  const u16* bl = fl + (size_t)(jbeg + l15) * C_DIM + kb;

  #pragma unroll 2
  for (int kk = 0; kk < C_DIM; kk += 32) {
    bf16x8 a0h = *(const bf16x8*)(ah + kk);
    bf16x8 a0l = *(const bf16x8*)(al + kk);
    bf16x8 a1h = *(const bf16x8*)(ah + R16 + kk);
    bf16x8 a1l = *(const bf16x8*)(al + R16 + kk);
    #pragma unroll
    for (int jt = 0; jt < 8; jt++) {
      bf16x8 vbh = *(const bf16x8*)(bh + jt * R16 + kk);
      bf16x8 vbl = *(const bf16x8*)(bl + jt * R16 + kk);
      acc[0][jt] = mfma16(a0h, vbh, acc[0][jt]);
      acc[0][jt] = mfma16(a0l, vbh, acc[0][jt]);
      acc[0][jt] = mfma16(a0h, vbl, acc[0][jt]);
      acc[1][jt] = mfma16(a1h, vbh, acc[1][jt]);
      acc[1][jt] = mfma16(a1l, vbh, acc[1][jt]);
      acc[1][jt] = mfma16(a1h, vbl, acc[1][jt]);
    }
  }

  // hoist x2[j] / j geometry (depends on jt, l15 only)
  float x2j[8]; int jy[8], jx[8];
  #pragma unroll
  for (int jt = 0; jt < 8; jt++) {
    int j = jbeg + jt * 16 + l15;
    x2j[jt] = x2[j];
    jy[jt] = j >> 6; jx[jt] = j & 63;
  }

  // per-row: sort8 own candidates, butterfly-merge 16 lanes, write
  #pragma unroll
  for (int sub = 0; sub < 2; sub++) {
    int rbase = i0 + sub * 16 + ((lane >> 4) << 2);
    #pragma unroll
    for (int r = 0; r < 4; r++) {
      int i = rbase + r;
      float x2i = x2[i];
      int iy = i >> 6, ix = i & 63;
      u64 key[8];
      #pragma unroll
      for (int jt = 0; jt < 8; jt++) {
        int j = jbeg + jt * 16 + l15;
        float d2 = x2i + x2j[jt] - 2.0f * acc[sub][jt][r];
        float fd = sqrtf(fmaxf(d2, 0.0f));
        float dy = (float)(iy - jy[jt]), dx = (float)(ix - jx[jt]);
        float sd = sqrtf(dy * dy + dx * dx);
        float comb = 0.7f * sd + 0.3f * fd;
        key[jt] = ((u64)__float_as_uint(comb) << 12) | (u64)j;
      }
      sort8(key);
      #pragma unroll
      for (int d = 1; d < 16; d <<= 1) {
        u64 o[8];
        #pragma unroll
        for (int q = 0; q < 8; q++) o[q] = __shfl_xor(key[q], d);
        merge8(key, o);
      }
      if (l15 == 0) {
        #pragma unroll
        for (int q = 0; q < 8; q++)
          pk[((size_t)blockIdx.y * N_NODES + i) * 8 + q] = key[q];
      }
    }
  }
}

// ---------------- merge 32 partial sorted lists + degree count ----------------
__global__ __launch_bounds__(256) void k_topk_merge(
    const u64* __restrict__ pk, int* __restrict__ tk, int* __restrict__ deg) {
  int n = blockIdx.x * 256 + threadIdx.x;
  if (n >= N_NODES) return;
  u64 r[8];
  #pragma unroll
  for (int q = 0; q < 8; q++) r[q] = KEY_INF;
  for (int c = 0; c < NCHUNK; c++) {
    const u64* lst = pk + ((size_t)c * N_NODES + n) * 8;
    #pragma unroll
    for (int q = 0; q < 8; q++) {
      u64 key = lst[q];
      if (key >= r[7]) break;
      ins8(key, r);
    }
  }
  #pragma unroll
  for (int o = 0; o < 8; o++) {
    int idx = (int)(r[o] & 0xFFF);
    tk[n * 8 + o] = idx;
    atomicAdd(&deg[idx], 1);
  }
}

// ---------------- exclusive scan (4096) + dinv ----------------
__global__ __launch_bounds__(256) void k_scan(const int* __restrict__ deg,
                                              int* __restrict__ offs,
                                              float* __restrict__ dinv) {
  __shared__ int ps[256];
  int t = threadIdx.x;
  int base = t * 16;
  int loc[16]; int s = 0;
  for (int i = 0; i < 16; i++) { int d = deg[base + i]; loc[i] = s; s += d; }
  ps[t] = s;
  __syncthreads();
  for (int d = 1; d < 256; d <<= 1) {
    int add = (t >= d) ? ps[t - d] : 0;
    __syncthreads();
    ps[t] += add;
    __syncthreads();
  }
  int cbase = (t == 0) ? 0 : ps[t - 1];
  for (int i = 0; i < 16; i++) offs[base + i] = cbase + loc[i];
  if (t == 255) offs[N_NODES] = ps[255];
  for (int i = 0; i < 16; i++)
    dinv[base + i] = 1.0f / sqrtf((float)deg[base + i]);
}

// ---------------- CSR fill ----------------
__global__ __launch_bounds__(256) void k_fill(const int* __restrict__ tk,
                                              const int* __restrict__ offs,
                                              int* __restrict__ cnt,
                                              int* __restrict__ insrc) {
  int e = blockIdx.x * 256 + threadIdx.x;
  if (e >= E_TOT) return;
  int i = e >> 3;
  int n = tk[e];
  int pos = offs[n] + atomicAdd(&cnt[n], 1);
  insrc[pos] = i;
}

// ---------------- per-node sort (determinism) ----------------
__global__ __launch_bounds__(256) void k_sort(const int* __restrict__ offs,
                                              int* __restrict__ insrc) {
  int n = blockIdx.x * 256 + threadIdx.x;
  if (n >= N_NODES) return;
  int beg = offs[n], end = offs[n + 1];
  for (int a = beg + 1; a < end; a++) {
    int v = insrc[a]; int p = a;
    while (p > beg && insrc[p - 1] > v) { insrc[p] = insrc[p - 1]; p--; }
    insrc[p] = v;
  }
}

// ---------------- bf16 MFMA GEMM, no LDS; wave = 64i x 64j ----------------
// EPI: 1 = bias+gelu -> bf16 out, 2 = bias+gelu -> f32 out, 3 = plain -> bf16 out
__device__ __forceinline__ float gelu_f(float x) {
  const float k0 = 0.7978845608028654f;  // sqrt(2/pi)
  float x3 = x * x * x;
  return 0.5f * x * (1.0f + tanhf(k0 * (x + 0.044715f * x3)));
}

template <int EPI>
__global__ __launch_bounds__(256) void k_gemm_mfma(
    const u16* __restrict__ A, const u16* __restrict__ Bt,
    const float* __restrict__ bias, void* __restrict__ Cout,
    int M, int N, int K) {
  int t = threadIdx.x, lane = t & 63, w = t >> 6;
  int m0 = blockIdx.x * 256 + w * 64;
  int n0 = blockIdx.y * 64;
  int l15 = lane & 15;
  int kb = (lane >> 4) * 8;

  f32x4 acc[4][4];
  #pragma unroll
  for (int s = 0; s < 4; s++)
    #pragma unroll
    for (int nt = 0; nt < 4; nt++) acc[s][nt] = (f32x4){0.f, 0.f, 0.f, 0.f};

  const u16* ap = A + (size_t)(m0 + l15) * K + kb;
  const u16* bp[4];
  #pragma unroll
  for (int nt = 0; nt < 4; nt++) {
    int nr = n0 + nt * 16 + l15;
    bp[nt] = Bt + (size_t)(nr < N ? nr : 0) * K + kb;
  }
  const size_t RA = (size_t)16 * K;

  for (int kk = 0; kk < K; kk += 32) {
    bf16x8 a[4], b[4];
    #pragma unroll
    for (int s = 0; s < 4; s++) a[s] = *(const bf16x8*)(ap + s * RA + kk);
    #pragma unroll
    for (int nt = 0; nt < 4; nt++) b[nt] = *(const bf16x8*)(bp[nt] + kk);
    #pragma unroll
    for (int s = 0; s < 4; s++)
      #pragma unroll
      for (int nt = 0; nt < 4; nt++)
        acc[s][nt] = mfma16(a[s], b[nt], acc[s][nt]);
  }

  #pragma unroll
  for (int s = 0; s < 4; s++) {
    int rbase = m0 + s * 16 + ((lane >> 4) << 2);
    #pragma unroll
    for (int nt = 0; nt < 4; nt++) {
      int n = n0 + nt * 16 + l15;
      if (n >= N) continue;
      float bb = (EPI == 1 || EPI == 2) ? bias[n] : 0.0f;
      #pragma unroll
      for (int r = 0; r < 4; r++) {
        int m = rbase + r;
        float v = acc[s][nt][r];
        if (EPI == 1 || EPI == 2) { v += bb; v = gelu_f(v); }
        if (EPI == 1 || EPI == 3)
          ((u16*)Cout)[(size_t)m * N + n] = f2bf(v);
        else
          ((float*)Cout)[(size_t)m * N + n] = v;
      }
    }
  }
}

// ---------------- GCN aggregation, vectorized: 4 ch/thread, 4 nodes/block ----------------
__global__ __launch_bounds__(384) void k_gcn_agg(
    const u16* __restrict__ xw, float* __restrict__ X, u16* __restrict__ Xb,
    const float* __restrict__ bias, const float* __restrict__ dinv,
    const int* __restrict__ offs, const int* __restrict__ insrc) {
  int t = threadIdx.x;
  int g = t / 96, l = t % 96;           // group g: one (b,n); lane l: 4 channels
  int bn = blockIdx.x * 4 + g;
  int b = bn >> 12, n = bn & 4095;
  int beg = offs[n], end = offs[n + 1];
  const u16* xwb = xw + (size_t)b * N_NODES * C_DIM + 4 * l;
  float s0 = 0.f, s1 = 0.f, s2 = 0.f, s3 = 0.f;
  for (int e = beg; e < end; e++) {
    int i = insrc[e];
    float dv = dinv[i];
    ushort4 v = *(const ushort4*)(xwb + (size_t)i * C_DIM);
    s0 += dv * bf2f(v.x);
    s1 += dv * bf2f(v.y);
    s2 += dv * bf2f(v.z);
    s3 += dv * bf2f(v.w);
  }
  float dn = dinv[n];
  int c = 4 * l;
  float4 b4 = *(const float4*)(bias + c);
  size_t o = (size_t)bn * C_DIM + c;
  float4 xo = *(float4*)(X + o);
  xo.x += fmaxf(dn * s0 + b4.x, 0.f);
  xo.y += fmaxf(dn * s1 + b4.y, 0.f);
  xo.z += fmaxf(dn * s2 + b4.z, 0.f);
  xo.w += fmaxf(dn * s3 + b4.w, 0.f);
  *(float4*)(X + o) = xo;
  ushort4 xb;
  xb.x = f2bf(xo.x); xb.y = f2bf(xo.y); xb.z = f2bf(xo.z); xb.w = f2bf(xo.w);
  *(ushort4*)(Xb + o) = xb;
}

// ---------------- final matvec (96 -> 1) + sigmoid ----------------
__global__ __launch_bounds__(256) void k_unc(
    const float* __restrict__ h2, const float* __restrict__ U3,
    const float* __restrict__ ub3, float* __restrict__ unc) {
  int r = blockIdx.x * 256 + threadIdx.x;
  if (r >= M_ROWS) return;
  const float4* h = (const float4*)(h2 + (size_t)r * 96);
  float s = 0.0f;
  #pragma unroll
  for (int c = 0; c < 24; c++) {
    float4 v = h[c];
    const float4 u = *(const float4*)(U3 + c * 4);
    s += v.x * u.x + v.y * u.y + v.z * u.z + v.w * u.w;
  }
  s += ub3[0];
  unc[r] = 1.0f / (1.0f + expf(-s));
}

// ---------------- out = fea * (1 + unc), float4 ----------------
__global__ __launch_bounds__(256) void k_final(
    const float* __restrict__ fea, const float* __restrict__ unc,
    float* __restrict__ out) {
  size_t i4 = (size_t)blockIdx.x * 256 + threadIdx.x;
  size_t idx = i4 * 4;
  if (idx >= (size_t)B_DIM * C_DIM * N_NODES) return;
  int b = (int)(idx / ((size_t)C_DIM * N_NODES));
  int n = (int)(idx & (N_NODES - 1));
  float4 f = *(const float4*)(fea + idx);
  float4 u = *(const float4*)(unc + (size_t)b * N_NODES + n);
  float4 o;
  o.x = f.x * (1.0f + u.x);
  o.y = f.y * (1.0f + u.y);
  o.z = f.z * (1.0f + u.z);
  o.w = f.w * (1.0f + u.w);
  *(float4*)(out + idx) = o;
}

extern "C" void kernel_launch(void* const* d_in, const int* in_sizes, int n_in,
                              void* d_out, int out_size, void* d_ws, size_t ws_size,
                              hipStream_t stream) {
  const float* fea = (const float*)d_in[0];
  const float* W1  = (const float*)d_in[1];
  const float* b1  = (const float*)d_in[2];
  const float* W2  = (const float*)d_in[3];
  const float* b2  = (const float*)d_in[4];
  const float* W3  = (const float*)d_in[5];
  const float* b3  = (const float*)d_in[6];
  const float* U1  = (const float*)d_in[7];
  const float* ub1 = (const float*)d_in[8];
  const float* U2  = (const float*)d_in[9];
  const float* ub2 = (const float*)d_in[10];
  const float* U3  = (const float*)d_in[11];
  const float* ub3 = (const float*)d_in[12];
  float* out = (float*)d_out;

  char* ws = (char*)d_ws;
  float* X    = (float*)(ws + 0);                       // 50331648
  u16*   Xb   = (u16*)  (ws + 50331648);                // 25165824
  u16*   XWb  = (u16*)  (ws + 75497472);                // 25165824
  u64*   pk   = (u64*)  (ws + 75497472);                // 8388608 (aliases XWb, pre-GEMM)
  u16*   h1b  = (u16*)  (ws + 75497472);                // 12582912 (aliases XWb, post-GCN)
  float* h2   = (float*)(ws + 75497472 + 12582912);     // 12582912
  u16*   fh   = (u16*)  (ws + 100663296);               // 3145728
  u16*   fl   = (u16*)  (ws + 103809024);               // 3145728
  float* x2   = (float*)(ws + 106954752);               // 16384
  int*   tk   = (int*)  (ws + 106971136);               // 131072
  int*   deg  = (int*)  (ws + 107102208);               // 16384
  float* dinv = (float*)(ws + 107118592);               // 16384
  int*   offs = (int*)  (ws + 107134976);               // 16896
  int*   cnt  = (int*)  (ws + 107151872);               // 16384
  int*   insrc= (int*)  (ws + 107168256);               // 131072
  float* unc  = (float*)(ws + 107299328);               // 131072
  u16*   Wt1  = (u16*)  (ws + 107430400);               // 294912
  u16*   Wt2  = (u16*)  (ws + 107725312);               // 294912
  u16*   Wt3  = (u16*)  (ws + 108020224);               // 294912
  u16*   U1t  = (u16*)  (ws + 108315136);               // 147456
  u16*   U2t  = (u16*)  (ws + 108462592);               // 36864

  // 0) weights -> transposed bf16
  k_prep_w<<<2088, 256, 0, stream>>>(W1, W2, W3, U1, U2, Wt1, Wt2, Wt3, U1t, U2t);
  // 1) transpose + mean (+ bf16)
  k_transpose_mean<<<dim3(N_NODES / 128, C_DIM / 32), dim3(32, 8), 0, stream>>>(
      fea, X, Xb, fh, fl);
  // 2) norms
  k_x2<<<N_NODES, 64, 0, stream>>>(fh, fl, x2);
  // 3) distance (3-term split-bf16 MFMA) + register top-8, then merge (+deg)
  hipMemsetAsync(deg, 0, N_NODES * 4, stream);
  hipMemsetAsync(cnt, 0, N_NODES * 4, stream);
  k_dist_topk<<<dim3(N_NODES / 128, NCHUNK), 256, 0, stream>>>(fh, fl, x2, pk);
  k_topk_merge<<<N_NODES / 256, 256, 0, stream>>>(pk, tk, deg);
  // 4) graph build
  k_scan<<<1, 256, 0, stream>>>(deg, offs, dinv);
  k_fill<<<E_TOT / 256, 256, 0, stream>>>(tk, offs, cnt, insrc);
  k_sort<<<N_NODES / 256, 256, 0, stream>>>(offs, insrc);
  // 5) three GCN layers (bf16 MFMA GEMM + aggregation)
  const u16* Wl[3] = {Wt1, Wt2, Wt3};
  const float* bl[3] = {b1, b2, b3};
  for (int l = 0; l < 3; l++) {
    k_gemm_mfma<3><<<dim3(M_ROWS / 256, C_DIM / 64), 256, 0, stream>>>(
        Xb, Wl[l], nullptr, XWb, M_ROWS, C_DIM, C_DIM);
    k_gcn_agg<<<M_ROWS / 4, 384, 0, stream>>>(XWb, X, Xb, bl[l], dinv, offs, insrc);
  }
  // 6) MLP
  k_gemm_mfma<1><<<dim3(M_ROWS / 256, 3), 256, 0, stream>>>(
      Xb, U1t, ub1, h1b, M_ROWS, 192, C_DIM);
  k_gemm_mfma<2><<<dim3(M_ROWS / 256, 2), 256, 0, stream>>>(
      h1b, U2t, ub2, h2, M_ROWS, 96, 192);
  k_unc<<<M_ROWS / 256, 256, 0, stream>>>(h2, U3, ub3, unc);
  // 7) output
  size_t tot = (size_t)B_DIM * C_DIM * N_NODES;
  k_final<<<(tot / 4 + 255) / 256, 256, 0, stream>>>(fea, unc, out);
}

// Round 5
// 439.665 us; speedup vs baseline: 4.3650x; 1.3442x over previous
//
#include <hip/hip_runtime.h>
#include <hip/hip_bf16.h>
#include <math.h>

#define N_NODES 4096
#define C_DIM   384
#define B_DIM   8
#define K_NB    8
#define E_TOT   (N_NODES * K_NB)     // 32768
#define M_ROWS  (B_DIM * N_NODES)    // 32768
#define NCHUNK  4                    // waves per row-merge (window kernel)

typedef unsigned long long u64;
typedef unsigned short u16;
typedef __attribute__((ext_vector_type(8))) short bf16x8;
typedef __attribute__((ext_vector_type(4))) float f32x4;
#define KEY_INF 0xFFFFFFFFFFFFFFFFull

__device__ __forceinline__ u16 f2bf(float f) {
  unsigned u = __float_as_uint(f);
  u += 0x7FFFu + ((u >> 16) & 1u);
  return (u16)(u >> 16);
}
__device__ __forceinline__ float bf2f(u16 h) {
  return __uint_as_float((unsigned)h << 16);
}
__device__ __forceinline__ f32x4 mfma16(bf16x8 a, bf16x8 b, f32x4 c) {
  return __builtin_amdgcn_mfma_f32_16x16x32_bf16(a, b, c, 0, 0, 0);
}

__device__ __forceinline__ void ce(u64& a, u64& b) {
  u64 lo = a < b ? a : b;
  u64 hi = a < b ? b : a;
  a = lo; b = hi;
}
// Batcher odd-even mergesort for 8 (19 comparators, branchless)
__device__ __forceinline__ void sort8(u64 (&k)[8]) {
  ce(k[0],k[1]); ce(k[2],k[3]); ce(k[4],k[5]); ce(k[6],k[7]);
  ce(k[0],k[2]); ce(k[1],k[3]); ce(k[4],k[6]); ce(k[5],k[7]);
  ce(k[1],k[2]); ce(k[5],k[6]);
  ce(k[0],k[4]); ce(k[1],k[5]); ce(k[2],k[6]); ce(k[3],k[7]);
  ce(k[2],k[4]); ce(k[3],k[5]);
  ce(k[1],k[2]); ce(k[3],k[4]); ce(k[5],k[6]);
}
__device__ __forceinline__ void ins8(u64 key, u64 (&r)[8]) {
  if (key < r[7]) {
    #pragma unroll
    for (int i = 0; i < 8; i++) {
      u64 lo = key < r[i] ? key : r[i];
      u64 hi = key < r[i] ? r[i] : key;
      r[i] = lo; key = hi;
    }
  }
}
// merge two ascending sorted-8 lists -> ascending 8 smallest
__device__ __forceinline__ void merge8(u64 (&r)[8], const u64 (&o)[8]) {
  u64 c[8];
  #pragma unroll
  for (int i = 0; i < 8; i++) c[i] = r[i] < o[7 - i] ? r[i] : o[7 - i];
  ce(c[0], c[4]); ce(c[1], c[5]); ce(c[2], c[6]); ce(c[3], c[7]);
  ce(c[0], c[2]); ce(c[1], c[3]); ce(c[4], c[6]); ce(c[5], c[7]);
  ce(c[0], c[1]); ce(c[2], c[3]); ce(c[4], c[5]); ce(c[6], c[7]);
  #pragma unroll
  for (int i = 0; i < 8; i++) r[i] = c[i];
}

// ---------------- weight prep: transpose + bf16 ----------------
__global__ __launch_bounds__(256) void k_prep_w(
    const float* __restrict__ W1, const float* __restrict__ W2,
    const float* __restrict__ W3, const float* __restrict__ U1,
    const float* __restrict__ U2,
    u16* __restrict__ Wt1, u16* __restrict__ Wt2, u16* __restrict__ Wt3,
    u16* __restrict__ U1t, u16* __restrict__ U2t) {
  int idx = blockIdx.x * 256 + threadIdx.x;
  if (idx < 147456) {
    int n = idx / 384, k = idx % 384;
    Wt1[idx] = f2bf(W1[k * 384 + n]);
  } else if (idx < 294912) {
    int i = idx - 147456; int n = i / 384, k = i % 384;
    Wt2[i] = f2bf(W2[k * 384 + n]);
  } else if (idx < 442368) {
    int i = idx - 294912; int n = i / 384, k = i % 384;
    Wt3[i] = f2bf(W3[k * 384 + n]);
  } else if (idx < 516096) {
    int i = idx - 442368; int n = i / 384, k = i % 384;
    U1t[i] = f2bf(U1[k * 192 + n]);
  } else if (idx < 534528) {
    int i = idx - 516096; int n = i / 192, k = i % 192;
    U2t[i] = f2bf(U2[k * 96 + n]);
  }
}

// ---------------- transpose + batch mean (+ bf16 splits), float4 reads ----------------
__global__ __launch_bounds__(256) void k_transpose_mean(
    const float* __restrict__ fea, float* __restrict__ X, u16* __restrict__ Xb,
    u16* __restrict__ fh, u16* __restrict__ fl) {
  __shared__ float tb[32][132];
  __shared__ float ac[32][132];
  int n0 = blockIdx.x * 128, c0 = blockIdx.y * 32;
  int tx = threadIdx.x, ty = threadIdx.y;   // (32,8)
  for (int i = ty; i < 32; i += 8) {
    #pragma unroll
    for (int e = 0; e < 4; e++) ac[i][tx * 4 + e] = 0.0f;
  }
  __syncthreads();
  for (int b = 0; b < B_DIM; b++) {
    for (int i = ty; i < 32; i += 8) {
      float4 v = *(const float4*)(fea +
          ((size_t)b * C_DIM + (c0 + i)) * N_NODES + n0 + tx * 4);
      *(float4*)&tb[i][tx * 4] = v;
      ac[i][tx * 4 + 0] += v.x;
      ac[i][tx * 4 + 1] += v.y;
      ac[i][tx * 4 + 2] += v.z;
      ac[i][tx * 4 + 3] += v.w;
    }
    __syncthreads();
    for (int rr = ty; rr < 128; rr += 8) {
      float v = tb[tx][rr];
      size_t o = ((size_t)b * N_NODES + (n0 + rr)) * C_DIM + c0 + tx;
      X[o] = v;
      Xb[o] = f2bf(v);
    }
    __syncthreads();
  }
  for (int rr = ty; rr < 128; rr += 8) {
    float m = ac[tx][rr] * 0.125f;
    u16 h = f2bf(m);
    size_t o = (size_t)(n0 + rr) * C_DIM + c0 + tx;
    fh[o] = h;
    fl[o] = f2bf(m - bf2f(h));
  }
}

// ---------------- squared norms (from hi+lo) ----------------
__global__ __launch_bounds__(64) void k_x2(const u16* __restrict__ fh,
                                           const u16* __restrict__ fl,
                                           float* __restrict__ x2) {
  int n = blockIdx.x;
  int lane = threadIdx.x;
  const u16* rh = fh + (size_t)n * C_DIM;
  const u16* rl = fl + (size_t)n * C_DIM;
  float s = 0.0f;
  for (int c = lane; c < C_DIM; c += 64) {
    float v = bf2f(rh[c]) + bf2f(rl[c]);
    s += v * v;
  }
  for (int d = 32; d > 0; d >>= 1) s += __shfl_down(s, d);
  if (lane == 0) x2[n] = s;
}

// ---------------- windowed distance + top-8 ----------------
// comb >= 0.7*sd, so any j with grid-distance >= 9 has comb >= 6.3. Each 4x4
// i-patch scans its 20x20 window (every i gets its full +-8 square). The merge
// kernel flags rows whose in-window 8th-best comb > 6.28 (=> window might not
// contain the global top-8) and k_fb redoes those rows exactly. grid: 512
// blocks of 128 (2 waves): block b -> patch b>>1; chunk c = (b&1)*2 + wave.
__global__ __launch_bounds__(128) void k_dist_win(
    const u16* __restrict__ fh, const u16* __restrict__ fl,
    const float* __restrict__ x2, u64* __restrict__ pk) {
  int t = threadIdx.x;
  int lane = t & 63, w = t >> 6;
  int p = blockIdx.x >> 1;
  int c = ((blockIdx.x & 1) << 1) | w;   // chunk 0..3
  int py = p >> 4, px = p & 15;          // 16x16 patch grid
  int iy0 = py * 4, ix0 = px * 4;
  int l15 = lane & 15;
  int kb = (lane >> 4) * 8;
  int t0 = (c == 0) ? 0 : 7 + (c - 1) * 6;  // tiles: 7,6,6,6 (25 total)
  int nt = c ? 6 : 7;

  // A rows = the 16 patch nodes; lane l15 -> node l15
  int arow = (iy0 + (l15 >> 2)) * 64 + (ix0 + (l15 & 3));
  const u16* ah = fh + (size_t)arow * C_DIM + kb;
  const u16* al = fl + (size_t)arow * C_DIM + kb;

  // B slots: slot s = tile*16 + l15; window (iy0-8..+12)x(ix0-8..+12)
  int jj[7]; const u16* bh[7]; const u16* bl[7];
  #pragma unroll
  for (int tt = 0; tt < 7; tt++) {
    int s = (t0 + tt) * 16 + l15;
    int sy = s / 20, sx = s - sy * 20;
    int jy = iy0 - 8 + sy, jx = ix0 - 8 + sx;
    bool v = (tt < nt) && ((unsigned)jy < 64u) && ((unsigned)jx < 64u);
    int j = jy * 64 + jx;
    jj[tt] = v ? j : -1;
    int jc = v ? j : 0;
    bh[tt] = fh + (size_t)jc * C_DIM + kb;
    bl[tt] = fl + (size_t)jc * C_DIM + kb;
  }

  f32x4 acc[7];
  #pragma unroll
  for (int tt = 0; tt < 7; tt++) acc[tt] = (f32x4){0.f, 0.f, 0.f, 0.f};

  #pragma unroll
  for (int kk = 0; kk < C_DIM; kk += 32) {
    bf16x8 a_h = *(const bf16x8*)(ah + kk);
    bf16x8 a_l = *(const bf16x8*)(al + kk);
    #pragma unroll
    for (int tt = 0; tt < 7; tt++) {
      bf16x8 b_h = *(const bf16x8*)(bh[tt] + kk);
      bf16x8 b_l = *(const bf16x8*)(bl[tt] + kk);
      acc[tt] = mfma16(a_h, b_h, acc[tt]);
      acc[tt] = mfma16(a_l, b_h, acc[tt]);
      acc[tt] = mfma16(a_h, b_l, acc[tt]);
    }
  }

  float x2j[7];
  #pragma unroll
  for (int tt = 0; tt < 7; tt++) x2j[tt] = (jj[tt] >= 0) ? x2[jj[tt]] : 0.0f;

  #pragma unroll
  for (int r = 0; r < 4; r++) {
    int r16 = ((lane >> 4) << 2) + r;
    int iy = iy0 + (r16 >> 2), ix = ix0 + (r16 & 3);
    int i = iy * 64 + ix;
    float x2i = x2[i];
    u64 key[8];
    #pragma unroll
    for (int tt = 0; tt < 7; tt++) {
      int j = jj[tt];
      float d2 = x2i + x2j[tt] - 2.0f * acc[tt][r];
      float fd = sqrtf(fmaxf(d2, 0.0f));
      float dy = (float)(iy - (j >> 6)), dx = (float)(ix - (j & 63));
      float sd = sqrtf(dy * dy + dx * dx);
      float comb = 0.7f * sd + 0.3f * fd;
      key[tt] = (j >= 0) ? (((u64)__float_as_uint(comb) << 12) | (u64)j)
                         : KEY_INF;
    }
    key[7] = KEY_INF;
    sort8(key);
    #pragma unroll
    for (int d = 1; d < 16; d <<= 1) {
      u64 o[8];
      #pragma unroll
      for (int q = 0; q < 8; q++) o[q] = __shfl_xor(key[q], d);
      merge8(key, o);
    }
    if (l15 == 0) {
      #pragma unroll
      for (int q = 0; q < 8; q++)
        pk[((size_t)c * N_NODES + i) * 8 + q] = key[q];
    }
  }
}

// ---------------- merge 4 partial lists; flag rows needing exact fallback ----------------
__global__ __launch_bounds__(256) void k_topk_merge(
    const u64* __restrict__ pk, int* __restrict__ tk, int* __restrict__ flag) {
  int n = blockIdx.x * 256 + threadIdx.x;
  if (n >= N_NODES) return;
  u64 r[8];
  #pragma unroll
  for (int q = 0; q < 8; q++) r[q] = KEY_INF;
  for (int c = 0; c < NCHUNK; c++) {
    const u64* lst = pk + ((size_t)c * N_NODES + n) * 8;
    #pragma unroll
    for (int q = 0; q < 8; q++) {
      u64 key = lst[q];
      if (key >= r[7]) break;
      ins8(key, r);
    }
  }
  #pragma unroll
  for (int o = 0; o < 8; o++) tk[n * 8 + o] = (int)(r[o] & 0xFFF);
  float c8 = __uint_as_float((unsigned)(r[7] >> 12));
  flag[n] = (c8 > 6.28f) ? 1 : 0;
}

// ---------------- exact fp32 full-scan fallback for flagged rows ----------------
__global__ __launch_bounds__(256) void k_fb(
    const u16* __restrict__ fh, const u16* __restrict__ fl,
    const float* __restrict__ x2, const int* __restrict__ flag,
    int* __restrict__ tk) {
  int w = threadIdx.x >> 6, lane = threadIdx.x & 63;
  for (int rr = 0; rr < 16; rr++) {
    int n = blockIdx.x * 64 + w * 16 + rr;
    if (!flag[n]) continue;
    u64 top[8];
    #pragma unroll
    for (int q = 0; q < 8; q++) top[q] = KEY_INF;
    float x2i = x2[n];
    int iy = n >> 6, ix = n & 63;
    const u16* rh = fh + (size_t)n * C_DIM;
    const u16* rl = fl + (size_t)n * C_DIM;
    for (int jb = 0; jb < N_NODES; jb += 64) {
      int j = jb + lane;
      const u16* ch = fh + (size_t)j * C_DIM;
      const u16* cl = fl + (size_t)j * C_DIM;
      float dot = 0.0f;
      for (int k2 = 0; k2 < C_DIM; k2++)
        dot += (bf2f(rh[k2]) + bf2f(rl[k2])) * (bf2f(ch[k2]) + bf2f(cl[k2]));
      float d2 = x2i + x2[j] - 2.0f * dot;
      float fd = sqrtf(fmaxf(d2, 0.0f));
      float dy = (float)(iy - (j >> 6)), dx = (float)(ix - (j & 63));
      float sd = sqrtf(dy * dy + dx * dx);
      float comb = 0.7f * sd + 0.3f * fd;
      ins8(((u64)__float_as_uint(comb) << 12) | (u64)j, top);
    }
    #pragma unroll
    for (int d = 1; d < 64; d <<= 1) {
      u64 o[8];
      #pragma unroll
      for (int q = 0; q < 8; q++) o[q] = __shfl_xor(top[q], d);
      merge8(top, o);
    }
    if (lane == 0) {
      #pragma unroll
      for (int q = 0; q < 8; q++) tk[n * 8 + q] = (int)(top[q] & 0xFFF);
    }
  }
}

// ---------------- degree count ----------------
__global__ __launch_bounds__(256) void k_deg(const int* __restrict__ tk,
                                             int* __restrict__ deg) {
  int e = blockIdx.x * 256 + threadIdx.x;
  if (e < E_TOT) atomicAdd(&deg[tk[e]], 1);
}

// ---------------- exclusive scan (4096) + dinv ----------------
__global__ __launch_bounds__(256) void k_scan(const int* __restrict__ deg,
                                              int* __restrict__ offs,
                                              float* __restrict__ dinv) {
  __shared__ int ps[256];
  int t = threadIdx.x;
  int base = t * 16;
  int loc[16]; int s = 0;
  for (int i = 0; i < 16; i++) { int d = deg[base + i]; loc[i] = s; s += d; }
  ps[t] = s;
  __syncthreads();
  for (int d = 1; d < 256; d <<= 1) {
    int add = (t >= d) ? ps[t - d] : 0;
    __syncthreads();
    ps[t] += add;
    __syncthreads();
  }
  int cbase = (t == 0) ? 0 : ps[t - 1];
  for (int i = 0; i < 16; i++) offs[base + i] = cbase + loc[i];
  if (t == 255) offs[N_NODES] = ps[255];
  for (int i = 0; i < 16; i++)
    dinv[base + i] = 1.0f / sqrtf((float)deg[base + i]);
}

// ---------------- CSR fill ----------------
__global__ __launch_bounds__(256) void k_fill(const int* __restrict__ tk,
                                              const int* __restrict__ offs,
                                              int* __restrict__ cnt,
                                              int* __restrict__ insrc) {
  int e = blockIdx.x * 256 + threadIdx.x;
  if (e >= E_TOT) return;
  int i = e >> 3;
  int n = tk[e];
  int pos = offs[n] + atomicAdd(&cnt[n], 1);
  insrc[pos] = i;
}

// ---------------- per-node sort (determinism) ----------------
__global__ __launch_bounds__(256) void k_sort(const int* __restrict__ offs,
                                              int* __restrict__ insrc) {
  int n = blockIdx.x * 256 + threadIdx.x;
  if (n >= N_NODES) return;
  int beg = offs[n], end = offs[n + 1];
  for (int a = beg + 1; a < end; a++) {
    int v = insrc[a]; int p = a;
    while (p > beg && insrc[p - 1] > v) { insrc[p] = insrc[p - 1]; p--; }
    insrc[p] = v;
  }
}

// ---------------- bf16 MFMA GEMM, no LDS; wave = 64i x 64j ----------------
// EPI: 1 = bias+gelu -> bf16 out, 2 = bias+gelu -> f32 out, 3 = plain -> bf16 out
__device__ __forceinline__ float gelu_f(float x) {
  const float k0 = 0.7978845608028654f;  // sqrt(2/pi)
  float x3 = x * x * x;
  return 0.5f * x * (1.0f + tanhf(k0 * (x + 0.044715f * x3)));
}

template <int EPI>
__global__ __launch_bounds__(256) void k_gemm_mfma(
    const u16* __restrict__ A, const u16* __restrict__ Bt,
    const float* __restrict__ bias, void* __restrict__ Cout,
    int M, int N, int K) {
  int t = threadIdx.x, lane = t & 63, w = t >> 6;
  int m0 = blockIdx.x * 256 + w * 64;
  int n0 = blockIdx.y * 64;
  int l15 = lane & 15;
  int kb = (lane >> 4) * 8;

  f32x4 acc[4][4];
  #pragma unroll
  for (int s = 0; s < 4; s++)
    #pragma unroll
    for (int nt = 0; nt < 4; nt++) acc[s][nt] = (f32x4){0.f, 0.f, 0.f, 0.f};

  const u16* ap = A + (size_t)(m0 + l15) * K + kb;
  const u16* bp[4];
  #pragma unroll
  for (int nt = 0; nt < 4; nt++) {
    int nr = n0 + nt * 16 + l15;
    bp[nt] = Bt + (size_t)(nr < N ? nr : 0) * K + kb;
  }
  const size_t RA = (size_t)16 * K;

  for (int kk = 0; kk < K; kk += 32) {
    bf16x8 a[4], b[4];
    #pragma unroll
    for (int s = 0; s < 4; s++) a[s] = *(const bf16x8*)(ap + s * RA + kk);
    #pragma unroll
    for (int nt = 0; nt < 4; nt++) b[nt] = *(const bf16x8*)(bp[nt] + kk);
    #pragma unroll
    for (int s = 0; s < 4; s++)
      #pragma unroll
      for (int nt = 0; nt < 4; nt++)
        acc[s][nt] = mfma16(a[s], b[nt], acc[s][nt]);
  }

  #pragma unroll
  for (int s = 0; s < 4; s++) {
    int rbase = m0 + s * 16 + ((lane >> 4) << 2);
    #pragma unroll
    for (int nt = 0; nt < 4; nt++) {
      int n = n0 + nt * 16 + l15;
      if (n >= N) continue;
      float bb = (EPI == 1 || EPI == 2) ? bias[n] : 0.0f;
      #pragma unroll
      for (int r = 0; r < 4; r++) {
        int m = rbase + r;
        float v = acc[s][nt][r];
        if (EPI == 1 || EPI == 2) { v += bb; v = gelu_f(v); }
        if (EPI == 1 || EPI == 3)
          ((u16*)Cout)[(size_t)m * N + n] = f2bf(v);
        else
          ((float*)Cout)[(size_t)m * N + n] = v;
      }
    }
  }
}

// ---------------- GCN aggregation, vectorized: 4 ch/thread, 4 nodes/block ----------------
__global__ __launch_bounds__(384) void k_gcn_agg(
    const u16* __restrict__ xw, float* __restrict__ X, u16* __restrict__ Xb,
    const float* __restrict__ bias, const float* __restrict__ dinv,
    const int* __restrict__ offs, const int* __restrict__ insrc) {
  int t = threadIdx.x;
  int g = t / 96, l = t % 96;           // group g: one (b,n); lane l: 4 channels
  int bn = blockIdx.x * 4 + g;
  int b = bn >> 12, n = bn & 4095;
  int beg = offs[n], end = offs[n + 1];
  const u16* xwb = xw + (size_t)b * N_NODES * C_DIM + 4 * l;
  float s0 = 0.f, s1 = 0.f, s2 = 0.f, s3 = 0.f;
  for (int e = beg; e < end; e++) {
    int i = insrc[e];
    float dv = dinv[i];
    ushort4 v = *(const ushort4*)(xwb + (size_t)i * C_DIM);
    s0 += dv * bf2f(v.x);
    s1 += dv * bf2f(v.y);
    s2 += dv * bf2f(v.z);
    s3 += dv * bf2f(v.w);
  }
  float dn = dinv[n];
  int c = 4 * l;
  float4 b4 = *(const float4*)(bias + c);
  size_t o = (size_t)bn * C_DIM + c;
  float4 xo = *(float4*)(X + o);
  xo.x += fmaxf(dn * s0 + b4.x, 0.f);
  xo.y += fmaxf(dn * s1 + b4.y, 0.f);
  xo.z += fmaxf(dn * s2 + b4.z, 0.f);
  xo.w += fmaxf(dn * s3 + b4.w, 0.f);
  *(float4*)(X + o) = xo;
  ushort4 xb;
  xb.x = f2bf(xo.x); xb.y = f2bf(xo.y); xb.z = f2bf(xo.z); xb.w = f2bf(xo.w);
  *(ushort4*)(Xb + o) = xb;
}

// ---------------- final matvec (96 -> 1) + sigmoid ----------------
__global__ __launch_bounds__(256) void k_unc(
    const float* __restrict__ h2, const float* __restrict__ U3,
    const float* __restrict__ ub3, float* __restrict__ unc) {
  int r = blockIdx.x * 256 + threadIdx.x;
  if (r >= M_ROWS) return;
  const float4* h = (const float4*)(h2 + (size_t)r * 96);
  float s = 0.0f;
  #pragma unroll
  for (int c = 0; c < 24; c++) {
    float4 v = h[c];
    const float4 u = *(const float4*)(U3 + c * 4);
    s += v.x * u.x + v.y * u.y + v.z * u.z + v.w * u.w;
  }
  s += ub3[0];
  unc[r] = 1.0f / (1.0f + expf(-s));
}

// ---------------- out = fea * (1 + unc), float4 ----------------
__global__ __launch_bounds__(256) void k_final(
    const float* __restrict__ fea, const float* __restrict__ unc,
    float* __restrict__ out) {
  size_t i4 = (size_t)blockIdx.x * 256 + threadIdx.x;
  size_t idx = i4 * 4;
  if (idx >= (size_t)B_DIM * C_DIM * N_NODES) return;
  int b = (int)(idx / ((size_t)C_DIM * N_NODES));
  int n = (int)(idx & (N_NODES - 1));
  float4 f = *(const float4*)(fea + idx);
  float4 u = *(const float4*)(unc + (size_t)b * N_NODES + n);
  float4 o;
  o.x = f.x * (1.0f + u.x);
  o.y = f.y * (1.0f + u.y);
  o.z = f.z * (1.0f + u.z);
  o.w = f.w * (1.0f + u.w);
  *(float4*)(out + idx) = o;
}

extern "C" void kernel_launch(void* const* d_in, const int* in_sizes, int n_in,
                              void* d_out, int out_size, void* d_ws, size_t ws_size,
                              hipStream_t stream) {
  const float* fea = (const float*)d_in[0];
  const float* W1  = (const float*)d_in[1];
  const float* b1  = (const float*)d_in[2];
  const float* W2  = (const float*)d_in[3];
  const float* b2  = (const float*)d_in[4];
  const float* W3  = (const float*)d_in[5];
  const float* b3  = (const float*)d_in[6];
  const float* U1  = (const float*)d_in[7];
  const float* ub1 = (const float*)d_in[8];
  const float* U2  = (const float*)d_in[9];
  const float* ub2 = (const float*)d_in[10];
  const float* U3  = (const float*)d_in[11];
  const float* ub3 = (const float*)d_in[12];
  float* out = (float*)d_out;

  char* ws = (char*)d_ws;
  float* X    = (float*)(ws + 0);                       // 50331648
  u16*   Xb   = (u16*)  (ws + 50331648);                // 25165824
  u16*   XWb  = (u16*)  (ws + 75497472);                // 25165824
  u64*   pk   = (u64*)  (ws + 75497472);                // 1048576 (aliases XWb, pre-GEMM)
  u16*   h1b  = (u16*)  (ws + 75497472);                // 12582912 (aliases XWb, post-GCN)
  float* h2   = (float*)(ws + 75497472 + 12582912);     // 12582912
  u16*   fh   = (u16*)  (ws + 100663296);               // 3145728
  u16*   fl   = (u16*)  (ws + 103809024);               // 3145728
  float* x2   = (float*)(ws + 106954752);               // 16384
  int*   tk   = (int*)  (ws + 106971136);               // 131072
  int*   deg  = (int*)  (ws + 107102208);               // 16384
  float* dinv = (float*)(ws + 107118592);               // 16384
  int*   offs = (int*)  (ws + 107134976);               // 16896
  int*   cnt  = (int*)  (ws + 107151872);               // 16384
  int*   insrc= (int*)  (ws + 107168256);               // 131072
  float* unc  = (float*)(ws + 107299328);               // 131072
  u16*   Wt1  = (u16*)  (ws + 107430400);               // 294912
  u16*   Wt2  = (u16*)  (ws + 107725312);               // 294912
  u16*   Wt3  = (u16*)  (ws + 108020224);               // 294912
  u16*   U1t  = (u16*)  (ws + 108315136);               // 147456
  u16*   U2t  = (u16*)  (ws + 108462592);               // 36864
  int*   flag = (int*)  (ws + 108499456);               // 16384

  // 0) weights -> transposed bf16
  k_prep_w<<<2088, 256, 0, stream>>>(W1, W2, W3, U1, U2, Wt1, Wt2, Wt3, U1t, U2t);
  // 1) transpose + mean (+ bf16)
  k_transpose_mean<<<dim3(N_NODES / 128, C_DIM / 32), dim3(32, 8), 0, stream>>>(
      fea, X, Xb, fh, fl);
  // 2) norms
  k_x2<<<N_NODES, 64, 0, stream>>>(fh, fl, x2);
  // 3) windowed distance top-8, merge(+flag), exact fallback, degrees
  hipMemsetAsync(deg, 0, N_NODES * 4, stream);
  hipMemsetAsync(cnt, 0, N_NODES * 4, stream);
  k_dist_win<<<512, 128, 0, stream>>>(fh, fl, x2, pk);
  k_topk_merge<<<N_NODES / 256, 256, 0, stream>>>(pk, tk, flag);
  k_fb<<<64, 256, 0, stream>>>(fh, fl, x2, flag, tk);
  k_deg<<<E_TOT / 256, 256, 0, stream>>>(tk, deg);
  // 4) graph build
  k_scan<<<1, 256, 0, stream>>>(deg, offs, dinv);
  k_fill<<<E_TOT / 256, 256, 0, stream>>>(tk, offs, cnt, insrc);
  k_sort<<<N_NODES / 256, 256, 0, stream>>>(offs, insrc);
  // 5) three GCN layers (bf16 MFMA GEMM + aggregation)
  const u16* Wl[3] = {Wt1, Wt2, Wt3};
  const float* bl[3] = {b1, b2, b3};
  for (int l = 0; l < 3; l++) {
    k_gemm_mfma<3><<<dim3(M_ROWS / 256, C_DIM / 64), 256, 0, stream>>>(
        Xb, Wl[l], nullptr, XWb, M_ROWS, C_DIM, C_DIM);
    k_gcn_agg<<<M_ROWS / 4, 384, 0, stream>>>(XWb, X, Xb, bl[l], dinv, offs, insrc);
  }
  // 6) MLP
  k_gemm_mfma<1><<<dim3(M_ROWS / 256, 3), 256, 0, stream>>>(
      Xb, U1t, ub1, h1b, M_ROWS, 192, C_DIM);
  k_gemm_mfma<2><<<dim3(M_ROWS / 256, 2), 256, 0, stream>>>(
      h1b, U2t, ub2, h2, M_ROWS, 96, 192);
  k_unc<<<M_ROWS / 256, 256, 0, stream>>>(h2, U3, ub3, unc);
  // 7) output
  size_t tot = (size_t)B_DIM * C_DIM * N_NODES;
  k_final<<<(tot / 4 + 255) / 256, 256, 0, stream>>>(fea, unc, out);
}

// Round 6
// 430.823 us; speedup vs baseline: 4.4546x; 1.0205x over previous
//
#include <hip/hip_runtime.h>
#include <hip/hip_bf16.h>
#include <math.h>

#define N_NODES 4096
#define C_DIM   384
#define B_DIM   8
#define K_NB    8
#define E_TOT   (N_NODES * K_NB)     // 32768
#define M_ROWS  (B_DIM * N_NODES)    // 32768
#define NCHUNK  4                    // waves per row-merge (window kernel)

typedef unsigned long long u64;
typedef unsigned short u16;
typedef __attribute__((ext_vector_type(8))) short bf16x8;
typedef __attribute__((ext_vector_type(4))) float f32x4;
#define KEY_INF 0xFFFFFFFFFFFFFFFFull

__device__ __forceinline__ u16 f2bf(float f) {
  unsigned u = __float_as_uint(f);
  u += 0x7FFFu + ((u >> 16) & 1u);
  return (u16)(u >> 16);
}
__device__ __forceinline__ float bf2f(u16 h) {
  return __uint_as_float((unsigned)h << 16);
}
__device__ __forceinline__ f32x4 mfma16(bf16x8 a, bf16x8 b, f32x4 c) {
  return __builtin_amdgcn_mfma_f32_16x16x32_bf16(a, b, c, 0, 0, 0);
}

__device__ __forceinline__ void ce(u64& a, u64& b) {
  u64 lo = a < b ? a : b;
  u64 hi = a < b ? b : a;
  a = lo; b = hi;
}
// Batcher odd-even mergesort for 8 (19 comparators, branchless)
__device__ __forceinline__ void sort8(u64 (&k)[8]) {
  ce(k[0],k[1]); ce(k[2],k[3]); ce(k[4],k[5]); ce(k[6],k[7]);
  ce(k[0],k[2]); ce(k[1],k[3]); ce(k[4],k[6]); ce(k[5],k[7]);
  ce(k[1],k[2]); ce(k[5],k[6]);
  ce(k[0],k[4]); ce(k[1],k[5]); ce(k[2],k[6]); ce(k[3],k[7]);
  ce(k[2],k[4]); ce(k[3],k[5]);
  ce(k[1],k[2]); ce(k[3],k[4]); ce(k[5],k[6]);
}
__device__ __forceinline__ void ins8(u64 key, u64 (&r)[8]) {
  if (key < r[7]) {
    #pragma unroll
    for (int i = 0; i < 8; i++) {
      u64 lo = key < r[i] ? key : r[i];
      u64 hi = key < r[i] ? r[i] : key;
      r[i] = lo; key = hi;
    }
  }
}
// merge two ascending sorted-8 lists -> ascending 8 smallest
__device__ __forceinline__ void merge8(u64 (&r)[8], const u64 (&o)[8]) {
  u64 c[8];
  #pragma unroll
  for (int i = 0; i < 8; i++) c[i] = r[i] < o[7 - i] ? r[i] : o[7 - i];
  ce(c[0], c[4]); ce(c[1], c[5]); ce(c[2], c[6]); ce(c[3], c[7]);
  ce(c[0], c[2]); ce(c[1], c[3]); ce(c[4], c[6]); ce(c[5], c[7]);
  ce(c[0], c[1]); ce(c[2], c[3]); ce(c[4], c[5]); ce(c[6], c[7]);
  #pragma unroll
  for (int i = 0; i < 8; i++) r[i] = c[i];
}

// ---------------- weight prep: transpose + bf16 ----------------
__global__ __launch_bounds__(256) void k_prep_w(
    const float* __restrict__ W1, const float* __restrict__ W2,
    const float* __restrict__ W3, const float* __restrict__ U1,
    const float* __restrict__ U2,
    u16* __restrict__ Wt1, u16* __restrict__ Wt2, u16* __restrict__ Wt3,
    u16* __restrict__ U1t, u16* __restrict__ U2t) {
  int idx = blockIdx.x * 256 + threadIdx.x;
  if (idx < 147456) {
    int n = idx / 384, k = idx % 384;
    Wt1[idx] = f2bf(W1[k * 384 + n]);
  } else if (idx < 294912) {
    int i = idx - 147456; int n = i / 384, k = i % 384;
    Wt2[i] = f2bf(W2[k * 384 + n]);
  } else if (idx < 442368) {
    int i = idx - 294912; int n = i / 384, k = i % 384;
    Wt3[i] = f2bf(W3[k * 384 + n]);
  } else if (idx < 516096) {
    int i = idx - 442368; int n = i / 384, k = i % 384;
    U1t[i] = f2bf(U1[k * 192 + n]);
  } else if (idx < 534528) {
    int i = idx - 516096; int n = i / 192, k = i % 192;
    U2t[i] = f2bf(U2[k * 96 + n]);
  }
}

// ---------------- transpose + batch mean -> Xb (bf16) + fh/fl ----------------
__global__ __launch_bounds__(256) void k_transpose_mean(
    const float* __restrict__ fea, u16* __restrict__ Xb,
    u16* __restrict__ fh, u16* __restrict__ fl) {
  __shared__ float tb[32][132];
  __shared__ float ac[32][132];
  int n0 = blockIdx.x * 128, c0 = blockIdx.y * 32;
  int tx = threadIdx.x, ty = threadIdx.y;   // (32,8)
  for (int i = ty; i < 32; i += 8) {
    #pragma unroll
    for (int e = 0; e < 4; e++) ac[i][tx * 4 + e] = 0.0f;
  }
  __syncthreads();
  for (int b = 0; b < B_DIM; b++) {
    for (int i = ty; i < 32; i += 8) {
      float4 v = *(const float4*)(fea +
          ((size_t)b * C_DIM + (c0 + i)) * N_NODES + n0 + tx * 4);
      *(float4*)&tb[i][tx * 4] = v;
      ac[i][tx * 4 + 0] += v.x;
      ac[i][tx * 4 + 1] += v.y;
      ac[i][tx * 4 + 2] += v.z;
      ac[i][tx * 4 + 3] += v.w;
    }
    __syncthreads();
    for (int rr = ty; rr < 128; rr += 8) {
      size_t o = ((size_t)b * N_NODES + (n0 + rr)) * C_DIM + c0 + tx;
      Xb[o] = f2bf(tb[tx][rr]);
    }
    __syncthreads();
  }
  for (int rr = ty; rr < 128; rr += 8) {
    float m = ac[tx][rr] * 0.125f;
    u16 h = f2bf(m);
    size_t o = (size_t)(n0 + rr) * C_DIM + c0 + tx;
    fh[o] = h;
    fl[o] = f2bf(m - bf2f(h));
  }
}

// ---------------- squared norms (from hi+lo) ----------------
__global__ __launch_bounds__(64) void k_x2(const u16* __restrict__ fh,
                                           const u16* __restrict__ fl,
                                           float* __restrict__ x2) {
  int n = blockIdx.x;
  int lane = threadIdx.x;
  const u16* rh = fh + (size_t)n * C_DIM;
  const u16* rl = fl + (size_t)n * C_DIM;
  float s = 0.0f;
  for (int c = lane; c < C_DIM; c += 64) {
    float v = bf2f(rh[c]) + bf2f(rl[c]);
    s += v * v;
  }
  for (int d = 32; d > 0; d >>= 1) s += __shfl_down(s, d);
  if (lane == 0) x2[n] = s;
}

// ---------------- windowed distance + top-8 ----------------
// comb >= 0.7*sd, so any j with grid-distance >= 9 has comb >= 6.3. Each 4x4
// i-patch scans its 20x20 window (every i gets its full +-8 square). The merge
// kernel flags rows whose in-window 8th-best comb > 6.28 and k_fb redoes those
// rows exactly. grid: 512 blocks of 128 (2 waves).
__global__ __launch_bounds__(128) void k_dist_win(
    const u16* __restrict__ fh, const u16* __restrict__ fl,
    const float* __restrict__ x2, u64* __restrict__ pk) {
  int t = threadIdx.x;
  int lane = t & 63, w = t >> 6;
  int p = blockIdx.x >> 1;
  int c = ((blockIdx.x & 1) << 1) | w;   // chunk 0..3
  int py = p >> 4, px = p & 15;          // 16x16 patch grid
  int iy0 = py * 4, ix0 = px * 4;
  int l15 = lane & 15;
  int kb = (lane >> 4) * 8;
  int t0 = (c == 0) ? 0 : 7 + (c - 1) * 6;  // tiles: 7,6,6,6 (25 total)
  int nt = c ? 6 : 7;

  // A rows = the 16 patch nodes; lane l15 -> node l15
  int arow = (iy0 + (l15 >> 2)) * 64 + (ix0 + (l15 & 3));
  const u16* ah = fh + (size_t)arow * C_DIM + kb;
  const u16* al = fl + (size_t)arow * C_DIM + kb;

  // B slots: slot s = tile*16 + l15; window (iy0-8..+12)x(ix0-8..+12)
  int jj[7]; const u16* bh[7]; const u16* bl[7];
  #pragma unroll
  for (int tt = 0; tt < 7; tt++) {
    int s = (t0 + tt) * 16 + l15;
    int sy = s / 20, sx = s - sy * 20;
    int jy = iy0 - 8 + sy, jx = ix0 - 8 + sx;
    bool v = (tt < nt) && ((unsigned)jy < 64u) && ((unsigned)jx < 64u);
    int j = jy * 64 + jx;
    jj[tt] = v ? j : -1;
    int jc = v ? j : 0;
    bh[tt] = fh + (size_t)jc * C_DIM + kb;
    bl[tt] = fl + (size_t)jc * C_DIM + kb;
  }

  f32x4 acc[7];
  #pragma unroll
  for (int tt = 0; tt < 7; tt++) acc[tt] = (f32x4){0.f, 0.f, 0.f, 0.f};

  #pragma unroll
  for (int kk = 0; kk < C_DIM; kk += 32) {
    bf16x8 a_h = *(const bf16x8*)(ah + kk);
    bf16x8 a_l = *(const bf16x8*)(al + kk);
    #pragma unroll
    for (int tt = 0; tt < 7; tt++) {
      bf16x8 b_h = *(const bf16x8*)(bh[tt] + kk);
      bf16x8 b_l = *(const bf16x8*)(bl[tt] + kk);
      acc[tt] = mfma16(a_h, b_h, acc[tt]);
      acc[tt] = mfma16(a_l, b_h, acc[tt]);
      acc[tt] = mfma16(a_h, b_l, acc[tt]);
    }
  }

  float x2j[7];
  #pragma unroll
  for (int tt = 0; tt < 7; tt++) x2j[tt] = (jj[tt] >= 0) ? x2[jj[tt]] : 0.0f;

  #pragma unroll
  for (int r = 0; r < 4; r++) {
    int r16 = ((lane >> 4) << 2) + r;
    int iy = iy0 + (r16 >> 2), ix = ix0 + (r16 & 3);
    int i = iy * 64 + ix;
    float x2i = x2[i];
    u64 key[8];
    #pragma unroll
    for (int tt = 0; tt < 7; tt++) {
      int j = jj[tt];
      float d2 = x2i + x2j[tt] - 2.0f * acc[tt][r];
      float fd = sqrtf(fmaxf(d2, 0.0f));
      float dy = (float)(iy - (j >> 6)), dx = (float)(ix - (j & 63));
      float sd = sqrtf(dy * dy + dx * dx);
      float comb = 0.7f * sd + 0.3f * fd;
      key[tt] = (j >= 0) ? (((u64)__float_as_uint(comb) << 12) | (u64)j)
                         : KEY_INF;
    }
    key[7] = KEY_INF;
    sort8(key);
    #pragma unroll
    for (int d = 1; d < 16; d <<= 1) {
      u64 o[8];
      #pragma unroll
      for (int q = 0; q < 8; q++) o[q] = __shfl_xor(key[q], d);
      merge8(key, o);
    }
    if (l15 == 0) {
      #pragma unroll
      for (int q = 0; q < 8; q++)
        pk[((size_t)c * N_NODES + i) * 8 + q] = key[q];
    }
  }
}

// ---------------- merge 4 partial lists; flag rows needing exact fallback ----------------
__global__ __launch_bounds__(256) void k_topk_merge(
    const u64* __restrict__ pk, int* __restrict__ tk, int* __restrict__ flag) {
  int n = blockIdx.x * 256 + threadIdx.x;
  if (n >= N_NODES) return;
  u64 r[8];
  #pragma unroll
  for (int q = 0; q < 8; q++) r[q] = KEY_INF;
  for (int c = 0; c < NCHUNK; c++) {
    const u64* lst = pk + ((size_t)c * N_NODES + n) * 8;
    #pragma unroll
    for (int q = 0; q < 8; q++) {
      u64 key = lst[q];
      if (key >= r[7]) break;
      ins8(key, r);
    }
  }
  #pragma unroll
  for (int o = 0; o < 8; o++) tk[n * 8 + o] = (int)(r[o] & 0xFFF);
  float c8 = __uint_as_float((unsigned)(r[7] >> 12));
  flag[n] = (c8 > 6.28f) ? 1 : 0;
}

// ---------------- exact fp32 full-scan fallback for flagged rows ----------------
__global__ __launch_bounds__(256) void k_fb(
    const u16* __restrict__ fh, const u16* __restrict__ fl,
    const float* __restrict__ x2, const int* __restrict__ flag,
    int* __restrict__ tk) {
  int w = threadIdx.x >> 6, lane = threadIdx.x & 63;
  for (int rr = 0; rr < 16; rr++) {
    int n = blockIdx.x * 64 + w * 16 + rr;
    if (!flag[n]) continue;
    u64 top[8];
    #pragma unroll
    for (int q = 0; q < 8; q++) top[q] = KEY_INF;
    float x2i = x2[n];
    int iy = n >> 6, ix = n & 63;
    const u16* rh = fh + (size_t)n * C_DIM;
    const u16* rl = fl + (size_t)n * C_DIM;
    for (int jb = 0; jb < N_NODES; jb += 64) {
      int j = jb + lane;
      const u16* ch = fh + (size_t)j * C_DIM;
      const u16* cl = fl + (size_t)j * C_DIM;
      float dot = 0.0f;
      for (int k2 = 0; k2 < C_DIM; k2++)
        dot += (bf2f(rh[k2]) + bf2f(rl[k2])) * (bf2f(ch[k2]) + bf2f(cl[k2]));
      float d2 = x2i + x2[j] - 2.0f * dot;
      float fd = sqrtf(fmaxf(d2, 0.0f));
      float dy = (float)(iy - (j >> 6)), dx = (float)(ix - (j & 63));
      float sd = sqrtf(dy * dy + dx * dx);
      float comb = 0.7f * sd + 0.3f * fd;
      ins8(((u64)__float_as_uint(comb) << 12) | (u64)j, top);
    }
    #pragma unroll
    for (int d = 1; d < 64; d <<= 1) {
      u64 o[8];
      #pragma unroll
      for (int q = 0; q < 8; q++) o[q] = __shfl_xor(top[q], d);
      merge8(top, o);
    }
    if (lane == 0) {
      #pragma unroll
      for (int q = 0; q < 8; q++) tk[n * 8 + q] = (int)(top[q] & 0xFFF);
    }
  }
}

// ---------------- degree count ----------------
__global__ __launch_bounds__(256) void k_deg(const int* __restrict__ tk,
                                             int* __restrict__ deg) {
  int e = blockIdx.x * 256 + threadIdx.x;
  if (e < E_TOT) atomicAdd(&deg[tk[e]], 1);
}

// ---------------- exclusive scan (4096) + dinv ----------------
__global__ __launch_bounds__(256) void k_scan(const int* __restrict__ deg,
                                              int* __restrict__ offs,
                                              float* __restrict__ dinv) {
  __shared__ int ps[256];
  int t = threadIdx.x;
  int base = t * 16;
  int loc[16]; int s = 0;
  for (int i = 0; i < 16; i++) { int d = deg[base + i]; loc[i] = s; s += d; }
  ps[t] = s;
  __syncthreads();
  for (int d = 1; d < 256; d <<= 1) {
    int add = (t >= d) ? ps[t - d] : 0;
    __syncthreads();
    ps[t] += add;
    __syncthreads();
  }
  int cbase = (t == 0) ? 0 : ps[t - 1];
  for (int i = 0; i < 16; i++) offs[base + i] = cbase + loc[i];
  if (t == 255) offs[N_NODES] = ps[255];
  for (int i = 0; i < 16; i++)
    dinv[base + i] = 1.0f / sqrtf((float)deg[base + i]);
}

// ---------------- CSR fill ----------------
__global__ __launch_bounds__(256) void k_fill(const int* __restrict__ tk,
                                              const int* __restrict__ offs,
                                              int* __restrict__ cnt,
                                              int* __restrict__ insrc) {
  int e = blockIdx.x * 256 + threadIdx.x;
  if (e >= E_TOT) return;
  int i = e >> 3;
  int n = tk[e];
  int pos = offs[n] + atomicAdd(&cnt[n], 1);
  insrc[pos] = i;
}

// ---------------- per-node sort (determinism) ----------------
__global__ __launch_bounds__(256) void k_sort(const int* __restrict__ offs,
                                              int* __restrict__ insrc) {
  int n = blockIdx.x * 256 + threadIdx.x;
  if (n >= N_NODES) return;
  int beg = offs[n], end = offs[n + 1];
  for (int a = beg + 1; a < end; a++) {
    int v = insrc[a]; int p = a;
    while (p > beg && insrc[p - 1] > v) { insrc[p] = insrc[p - 1]; p--; }
    insrc[p] = v;
  }
}

// ---------------- bf16 MFMA GEMM, no LDS; wave = 64i x 64j ----------------
// EPI: 1 = bias+gelu -> bf16 out, 2 = bias+gelu -> f32 out, 3 = plain -> bf16 out
__device__ __forceinline__ float gelu_f(float x) {
  const float k0 = 0.7978845608028654f;  // sqrt(2/pi)
  float x3 = x * x * x;
  return 0.5f * x * (1.0f + tanhf(k0 * (x + 0.044715f * x3)));
}

template <int EPI>
__global__ __launch_bounds__(256) void k_gemm_mfma(
    const u16* __restrict__ A, const u16* __restrict__ Bt,
    const float* __restrict__ bias, void* __restrict__ Cout,
    int M, int N, int K) {
  int t = threadIdx.x, lane = t & 63, w = t >> 6;
  int m0 = blockIdx.x * 256 + w * 64;
  int n0 = blockIdx.y * 64;
  int l15 = lane & 15;
  int kb = (lane >> 4) * 8;

  f32x4 acc[4][4];
  #pragma unroll
  for (int s = 0; s < 4; s++)
    #pragma unroll
    for (int nt = 0; nt < 4; nt++) acc[s][nt] = (f32x4){0.f, 0.f, 0.f, 0.f};

  const u16* ap = A + (size_t)(m0 + l15) * K + kb;
  const u16* bp[4];
  #pragma unroll
  for (int nt = 0; nt < 4; nt++) {
    int nr = n0 + nt * 16 + l15;
    bp[nt] = Bt + (size_t)(nr < N ? nr : 0) * K + kb;
  }
  const size_t RA = (size_t)16 * K;

  for (int kk = 0; kk < K; kk += 32) {
    bf16x8 a[4], b[4];
    #pragma unroll
    for (int s = 0; s < 4; s++) a[s] = *(const bf16x8*)(ap + s * RA + kk);
    #pragma unroll
    for (int nt = 0; nt < 4; nt++) b[nt] = *(const bf16x8*)(bp[nt] + kk);
    #pragma unroll
    for (int s = 0; s < 4; s++)
      #pragma unroll
      for (int nt = 0; nt < 4; nt++)
        acc[s][nt] = mfma16(a[s], b[nt], acc[s][nt]);
  }

  #pragma unroll
  for (int s = 0; s < 4; s++) {
    int rbase = m0 + s * 16 + ((lane >> 4) << 2);
    #pragma unroll
    for (int nt = 0; nt < 4; nt++) {
      int n = n0 + nt * 16 + l15;
      if (n >= N) continue;
      float bb = (EPI == 1 || EPI == 2) ? bias[n] : 0.0f;
      #pragma unroll
      for (int r = 0; r < 4; r++) {
        int m = rbase + r;
        float v = acc[s][nt][r];
        if (EPI == 1 || EPI == 2) { v += bb; v = gelu_f(v); }
        if (EPI == 1 || EPI == 3)
          ((u16*)Cout)[(size_t)m * N + n] = f2bf(v);
        else
          ((float*)Cout)[(size_t)m * N + n] = v;
      }
    }
  }
}

// ---------------- GCN aggregation: Xb += relu(...) (bf16 residual carrier) ----------------
__global__ __launch_bounds__(384) void k_gcn_agg(
    const u16* __restrict__ xw, u16* __restrict__ Xb,
    const float* __restrict__ bias, const float* __restrict__ dinv,
    const int* __restrict__ offs, const int* __restrict__ insrc) {
  int t = threadIdx.x;
  int g = t / 96, l = t % 96;           // group g: one (b,n); lane l: 4 channels
  int bn = blockIdx.x * 4 + g;
  int b = bn >> 12, n = bn & 4095;
  int beg = offs[n], end = offs[n + 1];
  const u16* xwb = xw + (size_t)b * N_NODES * C_DIM + 4 * l;
  float s0 = 0.f, s1 = 0.f, s2 = 0.f, s3 = 0.f;
  for (int e = beg; e < end; e++) {
    int i = insrc[e];
    float dv = dinv[i];
    ushort4 v = *(const ushort4*)(xwb + (size_t)i * C_DIM);
    s0 += dv * bf2f(v.x);
    s1 += dv * bf2f(v.y);
    s2 += dv * bf2f(v.z);
    s3 += dv * bf2f(v.w);
  }
  float dn = dinv[n];
  int c = 4 * l;
  float4 b4 = *(const float4*)(bias + c);
  size_t o = (size_t)bn * C_DIM + c;
  ushort4 xo = *(ushort4*)(Xb + o);
  ushort4 xn;
  xn.x = f2bf(bf2f(xo.x) + fmaxf(dn * s0 + b4.x, 0.f));
  xn.y = f2bf(bf2f(xo.y) + fmaxf(dn * s1 + b4.y, 0.f));
  xn.z = f2bf(bf2f(xo.z) + fmaxf(dn * s2 + b4.z, 0.f));
  xn.w = f2bf(bf2f(xo.w) + fmaxf(dn * s3 + b4.w, 0.f));
  *(ushort4*)(Xb + o) = xn;
}

// ---------------- final matvec (96 -> 1) + sigmoid ----------------
__global__ __launch_bounds__(256) void k_unc(
    const float* __restrict__ h2, const float* __restrict__ U3,
    const float* __restrict__ ub3, float* __restrict__ unc) {
  int r = blockIdx.x * 256 + threadIdx.x;
  if (r >= M_ROWS) return;
  const float4* h = (const float4*)(h2 + (size_t)r * 96);
  float s = 0.0f;
  #pragma unroll
  for (int c = 0; c < 24; c++) {
    float4 v = h[c];
    const float4 u = *(const float4*)(U3 + c * 4);
    s += v.x * u.x + v.y * u.y + v.z * u.z + v.w * u.w;
  }
  s += ub3[0];
  unc[r] = 1.0f / (1.0f + expf(-s));
}

// ---------------- out = fea * (1 + unc), float4 ----------------
__global__ __launch_bounds__(256) void k_final(
    const float* __restrict__ fea, const float* __restrict__ unc,
    float* __restrict__ out) {
  size_t i4 = (size_t)blockIdx.x * 256 + threadIdx.x;
  size_t idx = i4 * 4;
  if (idx >= (size_t)B_DIM * C_DIM * N_NODES) return;
  int b = (int)(idx / ((size_t)C_DIM * N_NODES));
  int n = (int)(idx & (N_NODES - 1));
  float4 f = *(const float4*)(fea + idx);
  float4 u = *(const float4*)(unc + (size_t)b * N_NODES + n);
  float4 o;
  o.x = f.x * (1.0f + u.x);
  o.y = f.y * (1.0f + u.y);
  o.z = f.z * (1.0f + u.z);
  o.w = f.w * (1.0f + u.w);
  *(float4*)(out + idx) = o;
}

extern "C" void kernel_launch(void* const* d_in, const int* in_sizes, int n_in,
                              void* d_out, int out_size, void* d_ws, size_t ws_size,
                              hipStream_t stream) {
  const float* fea = (const float*)d_in[0];
  const float* W1  = (const float*)d_in[1];
  const float* b1  = (const float*)d_in[2];
  const float* W2  = (const float*)d_in[3];
  const float* b2  = (const float*)d_in[4];
  const float* W3  = (const float*)d_in[5];
  const float* b3  = (const float*)d_in[6];
  const float* U1  = (const float*)d_in[7];
  const float* ub1 = (const float*)d_in[8];
  const float* U2  = (const float*)d_in[9];
  const float* ub2 = (const float*)d_in[10];
  const float* U3  = (const float*)d_in[11];
  const float* ub3 = (const float*)d_in[12];
  float* out = (float*)d_out;

  char* ws = (char*)d_ws;
  u16*   Xb   = (u16*)  (ws + 0);                       // 25165824
  u16*   XWb  = (u16*)  (ws + 25165824);                // 25165824
  u64*   pk   = (u64*)  (ws + 25165824);                // 1048576 (aliases XWb, pre-GEMM)
  u16*   h1b  = (u16*)  (ws + 25165824);                // 12582912 (aliases XWb, post-GCN)
  float* h2   = (float*)(ws + 25165824 + 12582912);     // 12582912
  u16*   fh   = (u16*)  (ws + 50331648);                // 3145728
  u16*   fl   = (u16*)  (ws + 53477376);                // 3145728
  float* x2   = (float*)(ws + 56623104);                // 16384
  int*   tk   = (int*)  (ws + 56639488);                // 131072
  int*   deg  = (int*)  (ws + 56770560);                // 16384
  float* dinv = (float*)(ws + 56786944);                // 16384
  int*   offs = (int*)  (ws + 56803328);                // 16896
  int*   cnt  = (int*)  (ws + 56820224);                // 16384
  int*   insrc= (int*)  (ws + 56836608);                // 131072
  float* unc  = (float*)(ws + 56967680);                // 131072
  u16*   Wt1  = (u16*)  (ws + 57098752);                // 294912
  u16*   Wt2  = (u16*)  (ws + 57393664);                // 294912
  u16*   Wt3  = (u16*)  (ws + 57688576);                // 294912
  u16*   U1t  = (u16*)  (ws + 57983488);                // 147456
  u16*   U2t  = (u16*)  (ws + 58130944);                // 36864
  int*   flag = (int*)  (ws + 58167808);                // 16384

  // 0) weights -> transposed bf16
  k_prep_w<<<2088, 256, 0, stream>>>(W1, W2, W3, U1, U2, Wt1, Wt2, Wt3, U1t, U2t);
  // 1) transpose + mean -> Xb, fh/fl
  k_transpose_mean<<<dim3(N_NODES / 128, C_DIM / 32), dim3(32, 8), 0, stream>>>(
      fea, Xb, fh, fl);
  // 2) norms
  k_x2<<<N_NODES, 64, 0, stream>>>(fh, fl, x2);
  // 3) windowed distance top-8, merge(+flag), exact fallback, degrees
  hipMemsetAsync(deg, 0, N_NODES * 4, stream);
  hipMemsetAsync(cnt, 0, N_NODES * 4, stream);
  k_dist_win<<<512, 128, 0, stream>>>(fh, fl, x2, pk);
  k_topk_merge<<<N_NODES / 256, 256, 0, stream>>>(pk, tk, flag);
  k_fb<<<64, 256, 0, stream>>>(fh, fl, x2, flag, tk);
  k_deg<<<E_TOT / 256, 256, 0, stream>>>(tk, deg);
  // 4) graph build
  k_scan<<<1, 256, 0, stream>>>(deg, offs, dinv);
  k_fill<<<E_TOT / 256, 256, 0, stream>>>(tk, offs, cnt, insrc);
  k_sort<<<N_NODES / 256, 256, 0, stream>>>(offs, insrc);
  // 5) three GCN layers (bf16 MFMA GEMM + aggregation, bf16 residual)
  const u16* Wl[3] = {Wt1, Wt2, Wt3};
  const float* bl[3] = {b1, b2, b3};
  for (int l = 0; l < 3; l++) {
    k_gemm_mfma<3><<<dim3(M_ROWS / 256, C_DIM / 64), 256, 0, stream>>>(
        Xb, Wl[l], nullptr, XWb, M_ROWS, C_DIM, C_DIM);
    k_gcn_agg<<<M_ROWS / 4, 384, 0, stream>>>(XWb, Xb, bl[l], dinv, offs, insrc);
  }
  // 6) MLP
  k_gemm_mfma<1><<<dim3(M_ROWS / 256, 3), 256, 0, stream>>>(
      Xb, U1t, ub1, h1b, M_ROWS, 192, C_DIM);
  k_gemm_mfma<2><<<dim3(M_ROWS / 256, 2), 256, 0, stream>>>(
      h1b, U2t, ub2, h2, M_ROWS, 96, 192);
  k_unc<<<M_ROWS / 256, 256, 0, stream>>>(h2, U3, ub3, unc);
  // 7) output
  size_t tot = (size_t)B_DIM * C_DIM * N_NODES;
  k_final<<<(tot / 4 + 255) / 256, 256, 0, stream>>>(fea, unc, out);
}

// Round 7
// 377.804 us; speedup vs baseline: 5.0797x; 1.1403x over previous
//
#include <hip/hip_runtime.h>
#include <hip/hip_bf16.h>
#include <math.h>

#define N_NODES 4096
#define C_DIM   384
#define B_DIM   8
#define K_NB    8
#define E_TOT   (N_NODES * K_NB)     // 32768
#define M_ROWS  (B_DIM * N_NODES)    // 32768
#define NCHUNK  4                    // waves per row-merge (window kernel)

typedef unsigned long long u64;
typedef unsigned short u16;
typedef __attribute__((ext_vector_type(8))) short bf16x8;
typedef __attribute__((ext_vector_type(4))) float f32x4;
#define KEY_INF 0xFFFFFFFFFFFFFFFFull

__device__ __forceinline__ u16 f2bf(float f) {
  unsigned u = __float_as_uint(f);
  u += 0x7FFFu + ((u >> 16) & 1u);
  return (u16)(u >> 16);
}
__device__ __forceinline__ float bf2f(u16 h) {
  return __uint_as_float((unsigned)h << 16);
}
__device__ __forceinline__ f32x4 mfma16(bf16x8 a, bf16x8 b, f32x4 c) {
  return __builtin_amdgcn_mfma_f32_16x16x32_bf16(a, b, c, 0, 0, 0);
}

__device__ __forceinline__ void ce(u64& a, u64& b) {
  u64 lo = a < b ? a : b;
  u64 hi = a < b ? b : a;
  a = lo; b = hi;
}
// Batcher odd-even mergesort for 8 (19 comparators, branchless)
__device__ __forceinline__ void sort8(u64 (&k)[8]) {
  ce(k[0],k[1]); ce(k[2],k[3]); ce(k[4],k[5]); ce(k[6],k[7]);
  ce(k[0],k[2]); ce(k[1],k[3]); ce(k[4],k[6]); ce(k[5],k[7]);
  ce(k[1],k[2]); ce(k[5],k[6]);
  ce(k[0],k[4]); ce(k[1],k[5]); ce(k[2],k[6]); ce(k[3],k[7]);
  ce(k[2],k[4]); ce(k[3],k[5]);
  ce(k[1],k[2]); ce(k[3],k[4]); ce(k[5],k[6]);
}
__device__ __forceinline__ void ins8(u64 key, u64 (&r)[8]) {
  if (key < r[7]) {
    #pragma unroll
    for (int i = 0; i < 8; i++) {
      u64 lo = key < r[i] ? key : r[i];
      u64 hi = key < r[i] ? r[i] : key;
      r[i] = lo; key = hi;
    }
  }
}
// merge two ascending sorted-8 lists -> ascending 8 smallest
__device__ __forceinline__ void merge8(u64 (&r)[8], const u64 (&o)[8]) {
  u64 c[8];
  #pragma unroll
  for (int i = 0; i < 8; i++) c[i] = r[i] < o[7 - i] ? r[i] : o[7 - i];
  ce(c[0], c[4]); ce(c[1], c[5]); ce(c[2], c[6]); ce(c[3], c[7]);
  ce(c[0], c[2]); ce(c[1], c[3]); ce(c[4], c[6]); ce(c[5], c[7]);
  ce(c[0], c[1]); ce(c[2], c[3]); ce(c[4], c[5]); ce(c[6], c[7]);
  #pragma unroll
  for (int i = 0; i < 8; i++) r[i] = c[i];
}

// ---------------- weight prep: transpose + bf16 ----------------
__global__ __launch_bounds__(256) void k_prep_w(
    const float* __restrict__ W1, const float* __restrict__ W2,
    const float* __restrict__ W3, const float* __restrict__ U1,
    const float* __restrict__ U2,
    u16* __restrict__ Wt1, u16* __restrict__ Wt2, u16* __restrict__ Wt3,
    u16* __restrict__ U1t, u16* __restrict__ U2t) {
  int idx = blockIdx.x * 256 + threadIdx.x;
  if (idx < 147456) {
    int n = idx / 384, k = idx % 384;
    Wt1[idx] = f2bf(W1[k * 384 + n]);
  } else if (idx < 294912) {
    int i = idx - 147456; int n = i / 384, k = i % 384;
    Wt2[i] = f2bf(W2[k * 384 + n]);
  } else if (idx < 442368) {
    int i = idx - 294912; int n = i / 384, k = i % 384;
    Wt3[i] = f2bf(W3[k * 384 + n]);
  } else if (idx < 516096) {
    int i = idx - 442368; int n = i / 384, k = i % 384;
    U1t[i] = f2bf(U1[k * 192 + n]);
  } else if (idx < 534528) {
    int i = idx - 516096; int n = i / 192, k = i % 192;
    U2t[i] = f2bf(U2[k * 96 + n]);
  }
}

// ---------------- transpose + batch mean -> Xb (bf16) + fh/fl ----------------
__global__ __launch_bounds__(256) void k_transpose_mean(
    const float* __restrict__ fea, u16* __restrict__ Xb,
    u16* __restrict__ fh, u16* __restrict__ fl) {
  __shared__ float tb[32][132];
  __shared__ float ac[32][132];
  int n0 = blockIdx.x * 128, c0 = blockIdx.y * 32;
  int tx = threadIdx.x, ty = threadIdx.y;   // (32,8)
  for (int i = ty; i < 32; i += 8) {
    #pragma unroll
    for (int e = 0; e < 4; e++) ac[i][tx * 4 + e] = 0.0f;
  }
  __syncthreads();
  for (int b = 0; b < B_DIM; b++) {
    for (int i = ty; i < 32; i += 8) {
      float4 v = *(const float4*)(fea +
          ((size_t)b * C_DIM + (c0 + i)) * N_NODES + n0 + tx * 4);
      *(float4*)&tb[i][tx * 4] = v;
      ac[i][tx * 4 + 0] += v.x;
      ac[i][tx * 4 + 1] += v.y;
      ac[i][tx * 4 + 2] += v.z;
      ac[i][tx * 4 + 3] += v.w;
    }
    __syncthreads();
    for (int rr = ty; rr < 128; rr += 8) {
      size_t o = ((size_t)b * N_NODES + (n0 + rr)) * C_DIM + c0 + tx;
      Xb[o] = f2bf(tb[tx][rr]);
    }
    __syncthreads();
  }
  for (int rr = ty; rr < 128; rr += 8) {
    float m = ac[tx][rr] * 0.125f;
    u16 h = f2bf(m);
    size_t o = (size_t)(n0 + rr) * C_DIM + c0 + tx;
    fh[o] = h;
    fl[o] = f2bf(m - bf2f(h));
  }
}

// ---------------- squared norms (from hi+lo) ----------------
__global__ __launch_bounds__(64) void k_x2(const u16* __restrict__ fh,
                                           const u16* __restrict__ fl,
                                           float* __restrict__ x2) {
  int n = blockIdx.x;
  int lane = threadIdx.x;
  const u16* rh = fh + (size_t)n * C_DIM;
  const u16* rl = fl + (size_t)n * C_DIM;
  float s = 0.0f;
  for (int c = lane; c < C_DIM; c += 64) {
    float v = bf2f(rh[c]) + bf2f(rl[c]);
    s += v * v;
  }
  for (int d = 32; d > 0; d >>= 1) s += __shfl_down(s, d);
  if (lane == 0) x2[n] = s;
}

// ---------------- windowed distance + top-8 ----------------
// comb >= 0.7*sd, so any j with grid-distance >= 9 has comb >= 6.3. Each 4x4
// i-patch scans its 20x20 window (every i gets its full +-8 square). The merge
// kernel flags rows whose in-window 8th-best comb > 6.28 and k_fb redoes those
// rows exactly. grid: 512 blocks of 128 (2 waves).
__global__ __launch_bounds__(128) void k_dist_win(
    const u16* __restrict__ fh, const u16* __restrict__ fl,
    const float* __restrict__ x2, u64* __restrict__ pk) {
  int t = threadIdx.x;
  int lane = t & 63, w = t >> 6;
  int p = blockIdx.x >> 1;
  int c = ((blockIdx.x & 1) << 1) | w;   // chunk 0..3
  int py = p >> 4, px = p & 15;          // 16x16 patch grid
  int iy0 = py * 4, ix0 = px * 4;
  int l15 = lane & 15;
  int kb = (lane >> 4) * 8;
  int t0 = (c == 0) ? 0 : 7 + (c - 1) * 6;  // tiles: 7,6,6,6 (25 total)
  int nt = c ? 6 : 7;

  // A rows = the 16 patch nodes; lane l15 -> node l15
  int arow = (iy0 + (l15 >> 2)) * 64 + (ix0 + (l15 & 3));
  const u16* ah = fh + (size_t)arow * C_DIM + kb;
  const u16* al = fl + (size_t)arow * C_DIM + kb;

  // B slots: slot s = tile*16 + l15; window (iy0-8..+12)x(ix0-8..+12)
  int jj[7]; const u16* bh[7]; const u16* bl[7];
  #pragma unroll
  for (int tt = 0; tt < 7; tt++) {
    int s = (t0 + tt) * 16 + l15;
    int sy = s / 20, sx = s - sy * 20;
    int jy = iy0 - 8 + sy, jx = ix0 - 8 + sx;
    bool v = (tt < nt) && ((unsigned)jy < 64u) && ((unsigned)jx < 64u);
    int j = jy * 64 + jx;
    jj[tt] = v ? j : -1;
    int jc = v ? j : 0;
    bh[tt] = fh + (size_t)jc * C_DIM + kb;
    bl[tt] = fl + (size_t)jc * C_DIM + kb;
  }

  f32x4 acc[7];
  #pragma unroll
  for (int tt = 0; tt < 7; tt++) acc[tt] = (f32x4){0.f, 0.f, 0.f, 0.f};

  #pragma unroll
  for (int kk = 0; kk < C_DIM; kk += 32) {
    bf16x8 a_h = *(const bf16x8*)(ah + kk);
    bf16x8 a_l = *(const bf16x8*)(al + kk);
    #pragma unroll
    for (int tt = 0; tt < 7; tt++) {
      bf16x8 b_h = *(const bf16x8*)(bh[tt] + kk);
      bf16x8 b_l = *(const bf16x8*)(bl[tt] + kk);
      acc[tt] = mfma16(a_h, b_h, acc[tt]);
      acc[tt] = mfma16(a_l, b_h, acc[tt]);
      acc[tt] = mfma16(a_h, b_l, acc[tt]);
    }
  }

  float x2j[7];
  #pragma unroll
  for (int tt = 0; tt < 7; tt++) x2j[tt] = (jj[tt] >= 0) ? x2[jj[tt]] : 0.0f;

  #pragma unroll
  for (int r = 0; r < 4; r++) {
    int r16 = ((lane >> 4) << 2) + r;
    int iy = iy0 + (r16 >> 2), ix = ix0 + (r16 & 3);
    int i = iy * 64 + ix;
    float x2i = x2[i];
    u64 key[8];
    #pragma unroll
    for (int tt = 0; tt < 7; tt++) {
      int j = jj[tt];
      float d2 = x2i + x2j[tt] - 2.0f * acc[tt][r];
      float fd = sqrtf(fmaxf(d2, 0.0f));
      float dy = (float)(iy - (j >> 6)), dx = (float)(ix - (j & 63));
      float sd = sqrtf(dy * dy + dx * dx);
      float comb = 0.7f * sd + 0.3f * fd;
      key[tt] = (j >= 0) ? (((u64)__float_as_uint(comb) << 12) | (u64)j)
                         : KEY_INF;
    }
    key[7] = KEY_INF;
    sort8(key);
    #pragma unroll
    for (int d = 1; d < 16; d <<= 1) {
      u64 o[8];
      #pragma unroll
      for (int q = 0; q < 8; q++) o[q] = __shfl_xor(key[q], d);
      merge8(key, o);
    }
    if (l15 == 0) {
      #pragma unroll
      for (int q = 0; q < 8; q++)
        pk[((size_t)c * N_NODES + i) * 8 + q] = key[q];
    }
  }
}

// ---------------- merge 4 partial lists; flag rows needing exact fallback ----------------
__global__ __launch_bounds__(256) void k_topk_merge(
    const u64* __restrict__ pk, int* __restrict__ tk, int* __restrict__ flag) {
  int n = blockIdx.x * 256 + threadIdx.x;
  if (n >= N_NODES) return;
  u64 r[8];
  #pragma unroll
  for (int q = 0; q < 8; q++) r[q] = KEY_INF;
  for (int c = 0; c < NCHUNK; c++) {
    const u64* lst = pk + ((size_t)c * N_NODES + n) * 8;
    #pragma unroll
    for (int q = 0; q < 8; q++) {
      u64 key = lst[q];
      if (key >= r[7]) break;
      ins8(key, r);
    }
  }
  #pragma unroll
  for (int o = 0; o < 8; o++) tk[n * 8 + o] = (int)(r[o] & 0xFFF);
  float c8 = __uint_as_float((unsigned)(r[7] >> 12));
  flag[n] = (c8 > 6.28f) ? 1 : 0;
}

// ---------------- exact fp32 full-scan fallback for flagged rows ----------------
__global__ __launch_bounds__(256) void k_fb(
    const u16* __restrict__ fh, const u16* __restrict__ fl,
    const float* __restrict__ x2, const int* __restrict__ flag,
    int* __restrict__ tk) {
  int w = threadIdx.x >> 6, lane = threadIdx.x & 63;
  for (int rr = 0; rr < 16; rr++) {
    int n = blockIdx.x * 64 + w * 16 + rr;
    if (!flag[n]) continue;
    u64 top[8];
    #pragma unroll
    for (int q = 0; q < 8; q++) top[q] = KEY_INF;
    float x2i = x2[n];
    int iy = n >> 6, ix = n & 63;
    const u16* rh = fh + (size_t)n * C_DIM;
    const u16* rl = fl + (size_t)n * C_DIM;
    for (int jb = 0; jb < N_NODES; jb += 64) {
      int j = jb + lane;
      const u16* ch = fh + (size_t)j * C_DIM;
      const u16* cl = fl + (size_t)j * C_DIM;
      float dot = 0.0f;
      for (int k2 = 0; k2 < C_DIM; k2++)
        dot += (bf2f(rh[k2]) + bf2f(rl[k2])) * (bf2f(ch[k2]) + bf2f(cl[k2]));
      float d2 = x2i + x2[j] - 2.0f * dot;
      float fd = sqrtf(fmaxf(d2, 0.0f));
      float dy = (float)(iy - (j >> 6)), dx = (float)(ix - (j & 63));
      float sd = sqrtf(dy * dy + dx * dx);
      float comb = 0.7f * sd + 0.3f * fd;
      ins8(((u64)__float_as_uint(comb) << 12) | (u64)j, top);
    }
    #pragma unroll
    for (int d = 1; d < 64; d <<= 1) {
      u64 o[8];
      #pragma unroll
      for (int q = 0; q < 8; q++) o[q] = __shfl_xor(top[q], d);
      merge8(top, o);
    }
    if (lane == 0) {
      #pragma unroll
      for (int q = 0; q < 8; q++) tk[n * 8 + q] = (int)(top[q] & 0xFFF);
    }
  }
}

// ---------------- degree count ----------------
__global__ __launch_bounds__(256) void k_deg(const int* __restrict__ tk,
                                             int* __restrict__ deg) {
  int e = blockIdx.x * 256 + threadIdx.x;
  if (e < E_TOT) atomicAdd(&deg[tk[e]], 1);
}

// ---------------- exclusive scan (4096) + dinv ----------------
__global__ __launch_bounds__(256) void k_scan(const int* __restrict__ deg,
                                              int* __restrict__ offs,
                                              float* __restrict__ dinv) {
  __shared__ int ps[256];
  int t = threadIdx.x;
  int base = t * 16;
  int loc[16]; int s = 0;
  for (int i = 0; i < 16; i++) { int d = deg[base + i]; loc[i] = s; s += d; }
  ps[t] = s;
  __syncthreads();
  for (int d = 1; d < 256; d <<= 1) {
    int add = (t >= d) ? ps[t - d] : 0;
    __syncthreads();
    ps[t] += add;
    __syncthreads();
  }
  int cbase = (t == 0) ? 0 : ps[t - 1];
  for (int i = 0; i < 16; i++) offs[base + i] = cbase + loc[i];
  if (t == 255) offs[N_NODES] = ps[255];
  for (int i = 0; i < 16; i++)
    dinv[base + i] = 1.0f / sqrtf((float)deg[base + i]);
}

// ---------------- CSR fill ----------------
__global__ __launch_bounds__(256) void k_fill(const int* __restrict__ tk,
                                              const int* __restrict__ offs,
                                              int* __restrict__ cnt,
                                              int* __restrict__ insrc) {
  int e = blockIdx.x * 256 + threadIdx.x;
  if (e >= E_TOT) return;
  int i = e >> 3;
  int n = tk[e];
  int pos = offs[n] + atomicAdd(&cnt[n], 1);
  insrc[pos] = i;
}

// ---------------- per-node sort (determinism) ----------------
__global__ __launch_bounds__(256) void k_sort(const int* __restrict__ offs,
                                              int* __restrict__ insrc) {
  int n = blockIdx.x * 256 + threadIdx.x;
  if (n >= N_NODES) return;
  int beg = offs[n], end = offs[n + 1];
  for (int a = beg + 1; a < end; a++) {
    int v = insrc[a]; int p = a;
    while (p > beg && insrc[p - 1] > v) { insrc[p] = insrc[p - 1]; p--; }
    insrc[p] = v;
  }
}

// ---------------- bf16 MFMA GEMM, no LDS; wave = 64i x 64j ----------------
// EPI: 1 = bias+gelu -> bf16 out, 2 = bias+gelu -> f32 out, 3 = plain -> bf16 out
__device__ __forceinline__ float gelu_f(float x) {
  const float k0 = 0.7978845608028654f;  // sqrt(2/pi)
  float x3 = x * x * x;
  return 0.5f * x * (1.0f + tanhf(k0 * (x + 0.044715f * x3)));
}

template <int EPI>
__global__ __launch_bounds__(256) void k_gemm_mfma(
    const u16* __restrict__ A, const u16* __restrict__ Bt,
    const float* __restrict__ bias, void* __restrict__ Cout,
    int M, int N, int K) {
  int t = threadIdx.x, lane = t & 63, w = t >> 6;
  int m0 = blockIdx.x * 256 + w * 64;
  int n0 = blockIdx.y * 64;
  int l15 = lane & 15;
  int kb = (lane >> 4) * 8;

  f32x4 acc[4][4];
  #pragma unroll
  for (int s = 0; s < 4; s++)
    #pragma unroll
    for (int nt = 0; nt < 4; nt++) acc[s][nt] = (f32x4){0.f, 0.f, 0.f, 0.f};

  const u16* ap = A + (size_t)(m0 + l15) * K + kb;
  const u16* bp[4];
  #pragma unroll
  for (int nt = 0; nt < 4; nt++) {
    int nr = n0 + nt * 16 + l15;
    bp[nt] = Bt + (size_t)(nr < N ? nr : 0) * K + kb;
  }
  const size_t RA = (size_t)16 * K;

  for (int kk = 0; kk < K; kk += 32) {
    bf16x8 a[4], b[4];
    #pragma unroll
    for (int s = 0; s < 4; s++) a[s] = *(const bf16x8*)(ap + s * RA + kk);
    #pragma unroll
    for (int nt = 0; nt < 4; nt++) b[nt] = *(const bf16x8*)(bp[nt] + kk);
    #pragma unroll
    for (int s = 0; s < 4; s++)
      #pragma unroll
      for (int nt = 0; nt < 4; nt++)
        acc[s][nt] = mfma16(a[s], b[nt], acc[s][nt]);
  }

  #pragma unroll
  for (int s = 0; s < 4; s++) {
    int rbase = m0 + s * 16 + ((lane >> 4) << 2);
    #pragma unroll
    for (int nt = 0; nt < 4; nt++) {
      int n = n0 + nt * 16 + l15;
      if (n >= N) continue;
      float bb = (EPI == 1 || EPI == 2) ? bias[n] : 0.0f;
      #pragma unroll
      for (int r = 0; r < 4; r++) {
        int m = rbase + r;
        float v = acc[s][nt][r];
        if (EPI == 1 || EPI == 2) { v += bb; v = gelu_f(v); }
        if (EPI == 1 || EPI == 3)
          ((u16*)Cout)[(size_t)m * N + n] = f2bf(v);
        else
          ((float*)Cout)[(size_t)m * N + n] = v;
      }
    }
  }
}

// ---------------- GCN aggregation, batch-fused: one node per 96-lane group,
// all 8 batch planes gathered per edge (8x memory-level parallelism) ----------------
__global__ __launch_bounds__(384) void k_gcn_agg(
    const u16* __restrict__ xw, u16* __restrict__ Xb,
    const float* __restrict__ bias, const float* __restrict__ dinv,
    const int* __restrict__ offs, const int* __restrict__ insrc) {
  const size_t PLANE = (size_t)N_NODES * C_DIM;
  int t = threadIdx.x;
  int g = t / 96, l = t % 96;           // group g: one node; lane l: 4 channels
  int n = blockIdx.x * 4 + g;
  int beg = offs[n], end = offs[n + 1];
  int c = 4 * l;
  const u16* base = xw + c;

  f32x4 a0 = {0,0,0,0}, a1 = {0,0,0,0}, a2 = {0,0,0,0}, a3 = {0,0,0,0};
  f32x4 a4 = {0,0,0,0}, a5 = {0,0,0,0}, a6 = {0,0,0,0}, a7 = {0,0,0,0};

  for (int e = beg; e < end; e++) {
    int i = insrc[e];
    float dv = dinv[i];
    const u16* rp = base + (size_t)i * C_DIM;
    ushort4 v0 = *(const ushort4*)(rp);
    ushort4 v1 = *(const ushort4*)(rp + PLANE);
    ushort4 v2 = *(const ushort4*)(rp + 2 * PLANE);
    ushort4 v3 = *(const ushort4*)(rp + 3 * PLANE);
    ushort4 v4 = *(const ushort4*)(rp + 4 * PLANE);
    ushort4 v5 = *(const ushort4*)(rp + 5 * PLANE);
    ushort4 v6 = *(const ushort4*)(rp + 6 * PLANE);
    ushort4 v7 = *(const ushort4*)(rp + 7 * PLANE);
    a0.x += dv * bf2f(v0.x); a0.y += dv * bf2f(v0.y); a0.z += dv * bf2f(v0.z); a0.w += dv * bf2f(v0.w);
    a1.x += dv * bf2f(v1.x); a1.y += dv * bf2f(v1.y); a1.z += dv * bf2f(v1.z); a1.w += dv * bf2f(v1.w);
    a2.x += dv * bf2f(v2.x); a2.y += dv * bf2f(v2.y); a2.z += dv * bf2f(v2.z); a2.w += dv * bf2f(v2.w);
    a3.x += dv * bf2f(v3.x); a3.y += dv * bf2f(v3.y); a3.z += dv * bf2f(v3.z); a3.w += dv * bf2f(v3.w);
    a4.x += dv * bf2f(v4.x); a4.y += dv * bf2f(v4.y); a4.z += dv * bf2f(v4.z); a4.w += dv * bf2f(v4.w);
    a5.x += dv * bf2f(v5.x); a5.y += dv * bf2f(v5.y); a5.z += dv * bf2f(v5.z); a5.w += dv * bf2f(v5.w);
    a6.x += dv * bf2f(v6.x); a6.y += dv * bf2f(v6.y); a6.z += dv * bf2f(v6.z); a6.w += dv * bf2f(v6.w);
    a7.x += dv * bf2f(v7.x); a7.y += dv * bf2f(v7.y); a7.z += dv * bf2f(v7.z); a7.w += dv * bf2f(v7.w);
  }

  float dn = dinv[n];
  float4 b4 = *(const float4*)(bias + c);
  size_t ob = (size_t)n * C_DIM + c;
  f32x4 av[8] = {a0, a1, a2, a3, a4, a5, a6, a7};
  #pragma unroll
  for (int b = 0; b < 8; b++) {
    size_t o = ob + (size_t)b * PLANE;
    ushort4 xo = *(ushort4*)(Xb + o);
    ushort4 xn;
    xn.x = f2bf(bf2f(xo.x) + fmaxf(dn * av[b].x + b4.x, 0.f));
    xn.y = f2bf(bf2f(xo.y) + fmaxf(dn * av[b].y + b4.y, 0.f));
    xn.z = f2bf(bf2f(xo.z) + fmaxf(dn * av[b].z + b4.z, 0.f));
    xn.w = f2bf(bf2f(xo.w) + fmaxf(dn * av[b].w + b4.w, 0.f));
    *(ushort4*)(Xb + o) = xn;
  }
}

// ---------------- final matvec (96 -> 1) + sigmoid ----------------
__global__ __launch_bounds__(256) void k_unc(
    const float* __restrict__ h2, const float* __restrict__ U3,
    const float* __restrict__ ub3, float* __restrict__ unc) {
  int r = blockIdx.x * 256 + threadIdx.x;
  if (r >= M_ROWS) return;
  const float4* h = (const float4*)(h2 + (size_t)r * 96);
  float s = 0.0f;
  #pragma unroll
  for (int c = 0; c < 24; c++) {
    float4 v = h[c];
    const float4 u = *(const float4*)(U3 + c * 4);
    s += v.x * u.x + v.y * u.y + v.z * u.z + v.w * u.w;
  }
  s += ub3[0];
  unc[r] = 1.0f / (1.0f + expf(-s));
}

// ---------------- out = fea * (1 + unc), float4 ----------------
__global__ __launch_bounds__(256) void k_final(
    const float* __restrict__ fea, const float* __restrict__ unc,
    float* __restrict__ out) {
  size_t i4 = (size_t)blockIdx.x * 256 + threadIdx.x;
  size_t idx = i4 * 4;
  if (idx >= (size_t)B_DIM * C_DIM * N_NODES) return;
  int b = (int)(idx / ((size_t)C_DIM * N_NODES));
  int n = (int)(idx & (N_NODES - 1));
  float4 f = *(const float4*)(fea + idx);
  float4 u = *(const float4*)(unc + (size_t)b * N_NODES + n);
  float4 o;
  o.x = f.x * (1.0f + u.x);
  o.y = f.y * (1.0f + u.y);
  o.z = f.z * (1.0f + u.z);
  o.w = f.w * (1.0f + u.w);
  *(float4*)(out + idx) = o;
}

extern "C" void kernel_launch(void* const* d_in, const int* in_sizes, int n_in,
                              void* d_out, int out_size, void* d_ws, size_t ws_size,
                              hipStream_t stream) {
  const float* fea = (const float*)d_in[0];
  const float* W1  = (const float*)d_in[1];
  const float* b1  = (const float*)d_in[2];
  const float* W2  = (const float*)d_in[3];
  const float* b2  = (const float*)d_in[4];
  const float* W3  = (const float*)d_in[5];
  const float* b3  = (const float*)d_in[6];
  const float* U1  = (const float*)d_in[7];
  const float* ub1 = (const float*)d_in[8];
  const float* U2  = (const float*)d_in[9];
  const float* ub2 = (const float*)d_in[10];
  const float* U3  = (const float*)d_in[11];
  const float* ub3 = (const float*)d_in[12];
  float* out = (float*)d_out;

  char* ws = (char*)d_ws;
  u16*   Xb   = (u16*)  (ws + 0);                       // 25165824
  u16*   XWb  = (u16*)  (ws + 25165824);                // 25165824
  u64*   pk   = (u64*)  (ws + 25165824);                // 1048576 (aliases XWb, pre-GEMM)
  u16*   h1b  = (u16*)  (ws + 25165824);                // 12582912 (aliases XWb, post-GCN)
  float* h2   = (float*)(ws + 25165824 + 12582912);     // 12582912
  u16*   fh   = (u16*)  (ws + 50331648);                // 3145728
  u16*   fl   = (u16*)  (ws + 53477376);                // 3145728
  float* x2   = (float*)(ws + 56623104);                // 16384
  int*   tk   = (int*)  (ws + 56639488);                // 131072
  int*   deg  = (int*)  (ws + 56770560);                // 16384
  float* dinv = (float*)(ws + 56786944);                // 16384
  int*   offs = (int*)  (ws + 56803328);                // 16896
  int*   cnt  = (int*)  (ws + 56820224);                // 16384
  int*   insrc= (int*)  (ws + 56836608);                // 131072
  float* unc  = (float*)(ws + 56967680);                // 131072
  u16*   Wt1  = (u16*)  (ws + 57098752);                // 294912
  u16*   Wt2  = (u16*)  (ws + 57393664);                // 294912
  u16*   Wt3  = (u16*)  (ws + 57688576);                // 294912
  u16*   U1t  = (u16*)  (ws + 57983488);                // 147456
  u16*   U2t  = (u16*)  (ws + 58130944);                // 36864
  int*   flag = (int*)  (ws + 58167808);                // 16384

  // 0) weights -> transposed bf16
  k_prep_w<<<2088, 256, 0, stream>>>(W1, W2, W3, U1, U2, Wt1, Wt2, Wt3, U1t, U2t);
  // 1) transpose + mean -> Xb, fh/fl
  k_transpose_mean<<<dim3(N_NODES / 128, C_DIM / 32), dim3(32, 8), 0, stream>>>(
      fea, Xb, fh, fl);
  // 2) norms
  k_x2<<<N_NODES, 64, 0, stream>>>(fh, fl, x2);
  // 3) windowed distance top-8, merge(+flag), exact fallback, degrees
  hipMemsetAsync(deg, 0, N_NODES * 4, stream);
  hipMemsetAsync(cnt, 0, N_NODES * 4, stream);
  k_dist_win<<<512, 128, 0, stream>>>(fh, fl, x2, pk);
  k_topk_merge<<<N_NODES / 256, 256, 0, stream>>>(pk, tk, flag);
  k_fb<<<64, 256, 0, stream>>>(fh, fl, x2, flag, tk);
  k_deg<<<E_TOT / 256, 256, 0, stream>>>(tk, deg);
  // 4) graph build
  k_scan<<<1, 256, 0, stream>>>(deg, offs, dinv);
  k_fill<<<E_TOT / 256, 256, 0, stream>>>(tk, offs, cnt, insrc);
  k_sort<<<N_NODES / 256, 256, 0, stream>>>(offs, insrc);
  // 5) three GCN layers (bf16 MFMA GEMM + batch-fused aggregation)
  const u16* Wl[3] = {Wt1, Wt2, Wt3};
  const float* bl[3] = {b1, b2, b3};
  for (int l = 0; l < 3; l++) {
    k_gemm_mfma<3><<<dim3(M_ROWS / 256, C_DIM / 64), 256, 0, stream>>>(
        Xb, Wl[l], nullptr, XWb, M_ROWS, C_DIM, C_DIM);
    k_gcn_agg<<<N_NODES / 4, 384, 0, stream>>>(XWb, Xb, bl[l], dinv, offs, insrc);
  }
  // 6) MLP
  k_gemm_mfma<1><<<dim3(M_ROWS / 256, 3), 256, 0, stream>>>(
      Xb, U1t, ub1, h1b, M_ROWS, 192, C_DIM);
  k_gemm_mfma<2><<<dim3(M_ROWS / 256, 2), 256, 0, stream>>>(
      h1b, U2t, ub2, h2, M_ROWS, 96, 192);
  k_unc<<<M_ROWS / 256, 256, 0, stream>>>(h2, U3, ub3, unc);
  // 7) output
  size_t tot = (size_t)B_DIM * C_DIM * N_NODES;
  k_final<<<(tot / 4 + 255) / 256, 256, 0, stream>>>(fea, unc, out);
}